// Round 1
// baseline (917.403 us; speedup 1.0000x reference)
//
#include <hip/hip_runtime.h>
#include <math.h>

#define HD 256          // hidden dim
#define BN 4096         // B*N nodes
#define N_PER_B 64
#define NE 16384        // edges
#define NSEL 65536      // selected pairs
#define NET 5           // edge types
#define PD 64           // property dim
#define PPB 32          // pairs per block in fused MLP

// ---------------------------------------------------------------------------
// Generic C[4096,256] = act( A0[4096,K0]@B0[K0,256] (+ A1[4096,256]@B1[256,256])
//                            + bias[256] + rowadd[m>>6][256] )
// 128x64 output tile per block, 256 threads, 8x4 microtile per thread.
// ---------------------------------------------------------------------------
__global__ __launch_bounds__(256, 2) void gemm_n256(
    const float* __restrict__ A0, const float* __restrict__ B0, int K0,
    const float* __restrict__ A1, const float* __restrict__ B1,
    const float* __restrict__ bias, const float* __restrict__ rowadd,
    float* __restrict__ C, int relu)
{
    __shared__ __align__(16) float As[16][128];
    __shared__ __align__(16) float Bs[16][64];
    const int tid = threadIdx.x;
    const int ty = tid >> 4;   // 0..15 -> rows ty*8..+7
    const int tx = tid & 15;   // cols tx*4..+3
    const int row0 = blockIdx.y * 128;
    const int col0 = blockIdx.x * 64;

    float acc[8][4];
    #pragma unroll
    for (int r = 0; r < 8; ++r)
        #pragma unroll
        for (int c = 0; c < 4; ++c) acc[r][c] = 0.f;

    for (int pass = 0; pass < 2; ++pass) {
        const float* A = pass ? A1 : A0;
        const float* B = pass ? B1 : B0;
        const int K = pass ? 256 : K0;
        if (A == nullptr) continue;           // wave-uniform branch
        for (int k0 = 0; k0 < K; k0 += 16) {
            // A tile: 128 rows x 16 k  (2 float4 loads/thread, transpose into As[k][row])
            {
                const int i = tid >> 1;           // row 0..127
                const int kq = (tid & 1) * 2;
                #pragma unroll
                for (int q = 0; q < 2; ++q) {
                    const int kk = (kq + q) * 4;
                    const float4 v = *(const float4*)(A + (row0 + i) * K + k0 + kk);
                    As[kk + 0][i] = v.x; As[kk + 1][i] = v.y;
                    As[kk + 2][i] = v.z; As[kk + 3][i] = v.w;
                }
            }
            // B tile: 16 k x 64 cols (1 float4/thread)
            {
                const int kk = tid >> 4;
                const int c4 = (tid & 15) * 4;
                *(float4*)&Bs[kk][c4] = *(const float4*)(B + (k0 + kk) * 256 + col0 + c4);
            }
            __syncthreads();
            #pragma unroll
            for (int k = 0; k < 16; ++k) {
                float a[8];
                const float4 av0 = *(const float4*)&As[k][ty * 8];
                const float4 av1 = *(const float4*)&As[k][ty * 8 + 4];
                a[0]=av0.x; a[1]=av0.y; a[2]=av0.z; a[3]=av0.w;
                a[4]=av1.x; a[5]=av1.y; a[6]=av1.z; a[7]=av1.w;
                const float4 bv = *(const float4*)&Bs[k][tx * 4];
                const float b[4] = {bv.x, bv.y, bv.z, bv.w};
                #pragma unroll
                for (int r = 0; r < 8; ++r)
                    #pragma unroll
                    for (int c = 0; c < 4; ++c)
                        acc[r][c] = fmaf(a[r], b[c], acc[r][c]);
            }
            __syncthreads();
        }
    }

    float badd[4] = {0.f, 0.f, 0.f, 0.f};
    if (bias) {
        const float4 bv = *(const float4*)(bias + col0 + tx * 4);
        badd[0]=bv.x; badd[1]=bv.y; badd[2]=bv.z; badd[3]=bv.w;
    }
    #pragma unroll
    for (int r = 0; r < 8; ++r) {
        const int m = row0 + ty * 8 + r;
        float v[4];
        #pragma unroll
        for (int c = 0; c < 4; ++c) v[c] = acc[r][c] + badd[c];
        if (rowadd) {
            const float4 rv = *(const float4*)(rowadd + (m >> 6) * 256 + col0 + tx * 4);
            v[0] += rv.x; v[1] += rv.y; v[2] += rv.z; v[3] += rv.w;
        }
        if (relu) {
            #pragma unroll
            for (int c = 0; c < 4; ++c) v[c] = fmaxf(v[c], 0.f);
        }
        float4 o; o.x=v[0]; o.y=v[1]; o.z=v[2]; o.w=v[3];
        *(float4*)(C + m * 256 + col0 + tx * 4) = o;
    }
}

// ---------------------------------------------------------------------------
// msg = relu(P[src] + edge_attr@Wme + b_msg); atomicAdd into agg[dst]
// one 64-lane wave group per edge, 4 cols per lane
// ---------------------------------------------------------------------------
__global__ __launch_bounds__(256) void edge_kernel(
    const float* __restrict__ P, const int* __restrict__ eidx,
    const float* __restrict__ eattr, const float* __restrict__ Wme,
    const float* __restrict__ bmsg, float* __restrict__ agg)
{
    const int e = blockIdx.x * 4 + (threadIdx.x >> 6);
    const int lane = threadIdx.x & 63;
    const int src = eidx[e];
    const int dst = eidx[NE + e];
    float a[NET];
    #pragma unroll
    for (int t = 0; t < NET; ++t) a[t] = eattr[e * NET + t];
    const int c = lane * 4;
    const float4 p  = *(const float4*)(P + src * 256 + c);
    const float4 bm = *(const float4*)(bmsg + c);
    float v[4] = {p.x + bm.x, p.y + bm.y, p.z + bm.z, p.w + bm.w};
    #pragma unroll
    for (int t = 0; t < NET; ++t) {
        const float4 w = *(const float4*)(Wme + t * 256 + c);
        v[0] = fmaf(a[t], w.x, v[0]);
        v[1] = fmaf(a[t], w.y, v[1]);
        v[2] = fmaf(a[t], w.z, v[2]);
        v[3] = fmaf(a[t], w.w, v[3]);
    }
    float* ag = agg + dst * 256 + c;
    atomicAdd(ag + 0, fmaxf(v[0], 0.f));
    atomicAdd(ag + 1, fmaxf(v[1], 0.f));
    atomicAdd(ag + 2, fmaxf(v[2], 0.f));
    atomicAdd(ag + 3, fmaxf(v[3], 0.f));
}

// ---------------------------------------------------------------------------
// prop_add[b][c] = sum_p (props[b]*W_prop[p] + b_prop[p]) * W_add[256+p][c] + b_add[c]
// ---------------------------------------------------------------------------
__global__ void prop_kernel(const float* __restrict__ props, const float* __restrict__ W_prop,
                            const float* __restrict__ b_prop, const float* __restrict__ W_add,
                            const float* __restrict__ b_add, float* __restrict__ prop_add)
{
    const int b = blockIdx.x;
    const int c = threadIdx.x;
    const float pv = props[b];
    float acc = b_add[c];
    for (int p = 0; p < PD; ++p) {
        const float e = fmaf(pv, W_prop[p], b_prop[p]);
        acc = fmaf(e, W_add[(256 + p) * 256 + c], acc);
    }
    prop_add[b * 256 + c] = acc;
}

// ---------------------------------------------------------------------------
// Wf[c][t] = sum_j W3[c][j]*W_out[j][t];  bf[t] = b3@W_out + b_out
// ---------------------------------------------------------------------------
__global__ void wf_kernel(const float* __restrict__ W3, const float* __restrict__ b3,
                          const float* __restrict__ W_out, const float* __restrict__ b_out,
                          float* __restrict__ Wf, float* __restrict__ bf)
{
    const int c = threadIdx.x;
    float acc[NET] = {0.f, 0.f, 0.f, 0.f, 0.f};
    for (int j = 0; j < 512; ++j) {
        const float w = W3[c * 512 + j];
        #pragma unroll
        for (int t = 0; t < NET; ++t) acc[t] = fmaf(w, W_out[j * NET + t], acc[t]);
    }
    #pragma unroll
    for (int t = 0; t < NET; ++t) Wf[c * NET + t] = acc[t];
    if (c == 0) {
        float s[NET];
        for (int t = 0; t < NET; ++t) s[t] = b_out[t];
        for (int j = 0; j < 512; ++j) {
            const float bj = b3[j];
            for (int t = 0; t < NET; ++t) s[t] = fmaf(bj, W_out[j * NET + t], s[t]);
        }
        for (int t = 0; t < NET; ++t) bf[t] = s[t];
    }
}

// ---------------------------------------------------------------------------
// Fused pair MLP + cross-entropy:
// h1 = relu(A1[s]+A2[d]+b1) in LDS; h2 = relu(h1@W2+b2); loss += lse - logit[g]
// 32 pairs/block; per thread: 2 pairs x 16 cols (cols = tx*4 + 64*j + i)
// ---------------------------------------------------------------------------
__global__ __launch_bounds__(256, 2) void pair_kernel(
    const float* __restrict__ A1t, const float* __restrict__ A2t,
    const float* __restrict__ b1, const float* __restrict__ W2,
    const float* __restrict__ b2, const float* __restrict__ Wf,
    const float* __restrict__ bf,
    const int* __restrict__ sel_b, const int* __restrict__ sel_i,
    const int* __restrict__ sel_j, const int* __restrict__ golden,
    float* __restrict__ out)
{
    __shared__ float h1s[PPB][257];               // pitch 257: conflict-free p-reads
    __shared__ __align__(16) float W2s[32][260];
    __shared__ __align__(16) float Wfs[NET][260]; // transposed Wf for float4 reads
    __shared__ __align__(16) float b2s[256];
    __shared__ float bfs[NET];
    __shared__ int sidx[PPB], didx[PPB], gold[PPB];
    __shared__ float red[16];

    const int tid = threadIdx.x;
    const int e0 = blockIdx.x * PPB;

    if (tid < PPB) {
        const int e = e0 + tid;
        const int b = sel_b[e];
        sidx[tid] = b * N_PER_B + sel_i[e];
        didx[tid] = b * N_PER_B + sel_j[e];
        gold[tid] = golden[e];
    }
    b2s[tid] = b2[tid];
    #pragma unroll
    for (int t = 0; t < NET; ++t) Wfs[t][tid] = Wf[tid * NET + t];
    if (tid < NET) bfs[tid] = bf[tid];
    __syncthreads();

    const float b1c = b1[tid];
    for (int p = 0; p < PPB; ++p) {
        const float v = A1t[sidx[p] * 256 + tid] + A2t[didx[p] * 256 + tid] + b1c;
        h1s[p][tid] = fmaxf(v, 0.f);
    }
    __syncthreads();

    const int py = tid >> 4;
    const int tx = tid & 15;
    const int p0 = 2 * py, p1 = p0 + 1;

    float acc[2][16];
    #pragma unroll
    for (int i = 0; i < 16; ++i) { acc[0][i] = 0.f; acc[1][i] = 0.f; }

    for (int k0 = 0; k0 < 256; k0 += 32) {
        #pragma unroll
        for (int q = 0; q < 8; ++q) {           // stage W2[k0..k0+31][0..255]
            const int idx = q * 1024 + tid * 4;
            const int kk = idx >> 8;
            const int cc = idx & 255;
            *(float4*)&W2s[kk][cc] = *(const float4*)(W2 + (k0 + kk) * 256 + cc);
        }
        __syncthreads();
        #pragma unroll 4
        for (int k = 0; k < 32; ++k) {
            const float a0v = h1s[p0][k0 + k];
            const float a1v = h1s[p1][k0 + k];
            #pragma unroll
            for (int j = 0; j < 4; ++j) {
                const float4 bv = *(const float4*)&W2s[k][tx * 4 + 64 * j];
                acc[0][j*4+0] = fmaf(a0v, bv.x, acc[0][j*4+0]);
                acc[0][j*4+1] = fmaf(a0v, bv.y, acc[0][j*4+1]);
                acc[0][j*4+2] = fmaf(a0v, bv.z, acc[0][j*4+2]);
                acc[0][j*4+3] = fmaf(a0v, bv.w, acc[0][j*4+3]);
                acc[1][j*4+0] = fmaf(a1v, bv.x, acc[1][j*4+0]);
                acc[1][j*4+1] = fmaf(a1v, bv.y, acc[1][j*4+1]);
                acc[1][j*4+2] = fmaf(a1v, bv.z, acc[1][j*4+2]);
                acc[1][j*4+3] = fmaf(a1v, bv.w, acc[1][j*4+3]);
            }
        }
        __syncthreads();
    }

    // epilogue: bias + relu + fold through Wf -> per-thread partial logits
    float pl[2][NET];
    #pragma unroll
    for (int p2 = 0; p2 < 2; ++p2)
        #pragma unroll
        for (int t = 0; t < NET; ++t) pl[p2][t] = 0.f;

    #pragma unroll
    for (int p2 = 0; p2 < 2; ++p2) {
        #pragma unroll
        for (int j = 0; j < 4; ++j) {
            const int colb = tx * 4 + 64 * j;
            const float4 b2v = *(const float4*)&b2s[colb];
            const float v0 = fmaxf(acc[p2][j*4+0] + b2v.x, 0.f);
            const float v1 = fmaxf(acc[p2][j*4+1] + b2v.y, 0.f);
            const float v2 = fmaxf(acc[p2][j*4+2] + b2v.z, 0.f);
            const float v3 = fmaxf(acc[p2][j*4+3] + b2v.w, 0.f);
            #pragma unroll
            for (int t = 0; t < NET; ++t) {
                const float4 wv = *(const float4*)&Wfs[t][colb];
                pl[p2][t] += v0 * wv.x + v1 * wv.y + v2 * wv.z + v3 * wv.w;
            }
        }
    }
    // reduce the 16 col-lanes of each pair group (lanes share py)
    #pragma unroll
    for (int p2 = 0; p2 < 2; ++p2)
        #pragma unroll
        for (int t = 0; t < NET; ++t) {
            float v = pl[p2][t];
            for (int off = 1; off < 16; off <<= 1) v += __shfl_xor(v, off, 16);
            pl[p2][t] = v;
        }

    if (tx == 0) {
        float lsum = 0.f;
        #pragma unroll
        for (int p2 = 0; p2 < 2; ++p2) {
            float lg[NET];
            #pragma unroll
            for (int t = 0; t < NET; ++t) lg[t] = pl[p2][t] + bfs[t];
            float m = lg[0];
            #pragma unroll
            for (int t = 1; t < NET; ++t) m = fmaxf(m, lg[t]);
            float s = 0.f;
            #pragma unroll
            for (int t = 0; t < NET; ++t) s += expf(lg[t] - m);
            const float lse = m + logf(s);
            lsum += lse - lg[gold[p0 + p2]];
        }
        red[py] = lsum;
    }
    __syncthreads();
    if (tid == 0) {
        float s = 0.f;
        #pragma unroll
        for (int i = 0; i < 16; ++i) s += red[i];
        atomicAdd(out, s * (1.0f / NSEL));
    }
}

// ---------------------------------------------------------------------------
extern "C" void kernel_launch(void* const* d_in, const int* in_sizes, int n_in,
                              void* d_out, int out_size, void* d_ws, size_t ws_size,
                              hipStream_t stream) {
    (void)in_sizes; (void)n_in; (void)out_size; (void)ws_size;
    const float* x      = (const float*)d_in[0];
    const int*   eidx   = (const int*)d_in[1];
    const float* eattr  = (const float*)d_in[2];
    const float* props  = (const float*)d_in[3];
    const int*   sel_b  = (const int*)d_in[4];
    const int*   sel_i  = (const int*)d_in[5];
    const int*   sel_j  = (const int*)d_in[6];
    const int*   golden = (const int*)d_in[7];
    const float* W_prop = (const float*)d_in[8];
    const float* b_prop = (const float*)d_in[9];
    const float* W_in   = (const float*)d_in[10];
    const float* b_in   = (const float*)d_in[11];
    const float* W_msg  = (const float*)d_in[12];
    const float* b_msg  = (const float*)d_in[13];
    const float* W_upd  = (const float*)d_in[14];
    const float* b_upd  = (const float*)d_in[15];
    const float* W_add  = (const float*)d_in[16];
    const float* b_add  = (const float*)d_in[17];
    const float* W1     = (const float*)d_in[18];
    const float* b1     = (const float*)d_in[19];
    const float* W2     = (const float*)d_in[20];
    const float* b2     = (const float*)d_in[21];
    const float* W3     = (const float*)d_in[22];
    const float* b3     = (const float*)d_in[23];
    const float* W_out  = (const float*)d_in[24];
    const float* b_out  = (const float*)d_in[25];

    float* ws = (float*)d_ws;
    const size_t SEG = (size_t)BN * 256;          // 1M floats per node-buffer
    float* bufA = ws;                             // h (even rounds)
    float* bufB = ws + SEG;                       // h (odd rounds) / A2
    float* bufC = ws + 2 * SEG;                   // P / node_embg
    float* bufD = ws + 3 * SEG;                   // agg / A1
    float* prop_add = ws + 4 * SEG;               // [64,256]
    float* Wf = prop_add + 64 * 256;              // [256,5]
    float* bf = Wf + 256 * NET;                   // [5]

    dim3 ggrid(4, 32);                            // 256/64 cols x 4096/128 rows

    // h = relu(x @ W_in + b_in)
    gemm_n256<<<ggrid, 256, 0, stream>>>(x, W_in, 192, nullptr, nullptr, b_in, nullptr, bufA, 1);

    float* hcur = bufA; float* halt = bufB;
    for (int t = 0; t < 4; ++t) {
        // P = h @ W_msg[0:256]
        gemm_n256<<<ggrid, 256, 0, stream>>>(hcur, W_msg, 256, nullptr, nullptr, nullptr, nullptr, bufC, 0);
        hipMemsetAsync(bufD, 0, SEG * sizeof(float), stream);
        edge_kernel<<<NE / 4, 256, 0, stream>>>(bufC, eidx, eattr, W_msg + 256 * 256, b_msg, bufD);
        // h = relu(h @ Wu_a + agg @ Wu_b + b_upd)
        gemm_n256<<<ggrid, 256, 0, stream>>>(hcur, W_upd, 256, bufD, W_upd + 256 * 256, b_upd, nullptr, halt, 1);
        float* tmp = hcur; hcur = halt; halt = tmp;
    }
    // after 4 rounds hcur == bufA, halt == bufB

    prop_kernel<<<N_PER_B, 256, 0, stream>>>(props, W_prop, b_prop, W_add, b_add, prop_add);
    // node_embg = h @ W_add[0:256] + prop_add[batch]   (b_add folded into prop_add)
    gemm_n256<<<ggrid, 256, 0, stream>>>(hcur, W_add, 256, nullptr, nullptr, nullptr, prop_add, bufC, 0);
    // A1 = embg @ W1[0:256], A2 = embg @ W1[256:512]
    gemm_n256<<<ggrid, 256, 0, stream>>>(bufC, W1, 256, nullptr, nullptr, nullptr, nullptr, bufD, 0);
    gemm_n256<<<ggrid, 256, 0, stream>>>(bufC, W1 + 256 * 256, 256, nullptr, nullptr, nullptr, nullptr, halt, 0);
    wf_kernel<<<1, 256, 0, stream>>>(W3, b3, W_out, b_out, Wf, bf);

    hipMemsetAsync(d_out, 0, sizeof(float), stream);
    pair_kernel<<<NSEL / PPB, 256, 0, stream>>>(bufD, halt, b1, W2, b2, Wf, bf,
                                                sel_b, sel_i, sel_j, golden, (float*)d_out);
}

// Round 2
// 618.000 us; speedup vs baseline: 1.4845x; 1.4845x over previous
//
#include <hip/hip_runtime.h>
#include <math.h>

#define HD 256
#define BN 4096
#define N_PER_B 64
#define NE 16384
#define NSEL 65536
#define NET 5
#define PD 64

typedef float f32x4 __attribute__((ext_vector_type(4)));
typedef short short8 __attribute__((ext_vector_type(8)));

__device__ inline unsigned short f2bf(float f) {
    unsigned int u = __builtin_bit_cast(unsigned int, f);
    u += 0x7fff + ((u >> 16) & 1);          // round-to-nearest-even
    return (unsigned short)(u >> 16);
}

// ---------------------------------------------------------------------------
// Weight convert + transpose: src fp32 [K][256] -> dst bf16 [256][K]
// blockIdx.y selects weight; 64x64 tiles via LDS.
// ---------------------------------------------------------------------------
__global__ __launch_bounds__(256) void conv_weights(
    const float* __restrict__ W_in, const float* __restrict__ W_msg,
    const float* __restrict__ W_upd, const float* __restrict__ W_add,
    const float* __restrict__ W1, const float* __restrict__ W2,
    unsigned short* __restrict__ dstbase)
{
    __shared__ float s[64][65];
    const int wsel = blockIdx.y;
    const float* src; unsigned short* dst; int K = 256;
    // dst offsets (shorts): W_inT 0 (256*192), then 7 x 65536
    switch (wsel) {
        case 0: src = W_in;              dst = dstbase;                      K = 192; break;
        case 1: src = W_msg;             dst = dstbase + 49152;              break;
        case 2: src = W_upd;             dst = dstbase + 49152 + 65536;      break;
        case 3: src = W_upd + 256 * 256; dst = dstbase + 49152 + 2 * 65536;  break;
        case 4: src = W_add;             dst = dstbase + 49152 + 3 * 65536;  break;
        case 5: src = W1;                dst = dstbase + 49152 + 4 * 65536;  break;
        case 6: src = W1 + 256 * 256;    dst = dstbase + 49152 + 5 * 65536;  break;
        default: src = W2;               dst = dstbase + 49152 + 6 * 65536;  break;
    }
    const int k0 = (blockIdx.x >> 2) * 64;
    const int n0 = (blockIdx.x & 3) * 64;
    if (k0 >= K) return;
    const int tn = threadIdx.x & 63;
    const int tg = threadIdx.x >> 6;
    #pragma unroll
    for (int i = 0; i < 16; ++i) {
        const int kk = tg * 16 + i;
        s[kk][tn] = src[(size_t)(k0 + kk) * 256 + n0 + tn];
    }
    __syncthreads();
    #pragma unroll
    for (int i = 0; i < 16; ++i) {
        const int nn = tg * 16 + i;
        dst[(size_t)(n0 + nn) * K + k0 + tn] = f2bf(s[tn][nn]);
    }
}

// ---------------------------------------------------------------------------
// MFMA node GEMM: C[4096,256] = act( A0@W0 (+ A1@W1) + bias + rowadd[batch] )
// A fp32 row-major [4096][K]; WT bf16 [256][K] (pre-transposed).
// Block tile 64 rows x 128 cols; grid (2, 64); 4 waves, wave = 16 rows.
// ---------------------------------------------------------------------------
__global__ __launch_bounds__(256, 2) void gemm_mfma(
    const float* __restrict__ A0, const unsigned short* __restrict__ WT0, int K0,
    const float* __restrict__ A1, const unsigned short* __restrict__ WT1,
    const float* __restrict__ bias, const float* __restrict__ rowadd,
    float* __restrict__ C, int relu)
{
    __shared__ __align__(16) unsigned short As[64 * 40];   // stride 40 shorts
    __shared__ __align__(16) unsigned short Bs[128 * 40];
    const int tid = threadIdx.x;
    const int w = tid >> 6;
    const int lane = tid & 63;
    const int q = lane >> 4;
    const int tx = lane & 15;
    const int row0 = blockIdx.y * 64;
    const int col0 = blockIdx.x * 128;

    f32x4 acc[8];
    #pragma unroll
    for (int c = 0; c < 8; ++c) acc[c] = (f32x4)0.f;

    for (int pass = 0; pass < 2; ++pass) {
        const float* A = pass ? A1 : A0;
        const unsigned short* WT = pass ? WT1 : WT0;
        const int K = pass ? 256 : K0;
        if (A == nullptr) continue;
        for (int k0 = 0; k0 < K; k0 += 32) {
            {   // stage A: 64 rows x 32 k, fp32 -> bf16
                const int r = tid >> 2;
                const int kq = (tid & 3) * 8;
                const float* ap = A + (size_t)(row0 + r) * K + k0 + kq;
                const float4 v0 = *(const float4*)ap;
                const float4 v1 = *(const float4*)(ap + 4);
                int4 pk;
                pk.x = f2bf(v0.x) | (f2bf(v0.y) << 16);
                pk.y = f2bf(v0.z) | (f2bf(v0.w) << 16);
                pk.z = f2bf(v1.x) | (f2bf(v1.y) << 16);
                pk.w = f2bf(v1.z) | (f2bf(v1.w) << 16);
                *(int4*)&As[r * 40 + kq] = pk;
            }
            {   // stage B: 128 cols x 32 k, already bf16
                const int n = tid >> 1;
                const int kq = (tid & 1) * 16;
                const int4* bp = (const int4*)(WT + (size_t)(col0 + n) * K + k0 + kq);
                const int4 b0 = bp[0];
                const int4 b1 = bp[1];
                *(int4*)&Bs[n * 40 + kq] = b0;
                *(int4*)&Bs[n * 40 + kq + 8] = b1;
            }
            __syncthreads();
            const short8 af = *(const short8*)&As[(w * 16 + tx) * 40 + q * 8];
            #pragma unroll
            for (int c = 0; c < 8; ++c) {
                const short8 bf = *(const short8*)&Bs[(c * 16 + tx) * 40 + q * 8];
                acc[c] = __builtin_amdgcn_mfma_f32_16x16x32_bf16(af, bf, acc[c], 0, 0, 0);
            }
            __syncthreads();
        }
    }

    const int bidx = row0 >> 6;   // all 64 rows in this tile share the batch index
    #pragma unroll
    for (int c = 0; c < 8; ++c) {
        const int col = col0 + c * 16 + tx;
        float badd = bias ? bias[col] : 0.f;
        if (rowadd) badd += rowadd[bidx * 256 + col];
        #pragma unroll
        for (int r = 0; r < 4; ++r) {
            const int m = row0 + w * 16 + q * 4 + r;
            float v = acc[c][r] + badd;
            if (relu) v = fmaxf(v, 0.f);
            C[(size_t)m * 256 + col] = v;
        }
    }
}

// ---------------------------------------------------------------------------
// msg = relu(P[src] + edge_attr@Wme + b_msg); atomicAdd into agg[dst] (fp32)
// ---------------------------------------------------------------------------
__global__ __launch_bounds__(256) void edge_kernel(
    const float* __restrict__ P, const int* __restrict__ eidx,
    const float* __restrict__ eattr, const float* __restrict__ Wme,
    const float* __restrict__ bmsg, float* __restrict__ agg)
{
    const int e = blockIdx.x * 4 + (threadIdx.x >> 6);
    const int lane = threadIdx.x & 63;
    const int src = eidx[e];
    const int dst = eidx[NE + e];
    float a[NET];
    #pragma unroll
    for (int t = 0; t < NET; ++t) a[t] = eattr[e * NET + t];
    const int c = lane * 4;
    const float4 p  = *(const float4*)(P + (size_t)src * 256 + c);
    const float4 bm = *(const float4*)(bmsg + c);
    float v[4] = {p.x + bm.x, p.y + bm.y, p.z + bm.z, p.w + bm.w};
    #pragma unroll
    for (int t = 0; t < NET; ++t) {
        const float4 wv = *(const float4*)(Wme + t * 256 + c);
        v[0] = fmaf(a[t], wv.x, v[0]);
        v[1] = fmaf(a[t], wv.y, v[1]);
        v[2] = fmaf(a[t], wv.z, v[2]);
        v[3] = fmaf(a[t], wv.w, v[3]);
    }
    float* ag = agg + (size_t)dst * 256 + c;
    atomicAdd(ag + 0, fmaxf(v[0], 0.f));
    atomicAdd(ag + 1, fmaxf(v[1], 0.f));
    atomicAdd(ag + 2, fmaxf(v[2], 0.f));
    atomicAdd(ag + 3, fmaxf(v[3], 0.f));
}

// ---------------------------------------------------------------------------
__global__ void prop_kernel(const float* __restrict__ props, const float* __restrict__ W_prop,
                            const float* __restrict__ b_prop, const float* __restrict__ W_add,
                            const float* __restrict__ b_add, float* __restrict__ prop_add)
{
    const int b = blockIdx.x;
    const int c = threadIdx.x;
    const float pv = props[b];
    float acc = b_add[c];
    for (int p = 0; p < PD; ++p) {
        const float e = fmaf(pv, W_prop[p], b_prop[p]);
        acc = fmaf(e, W_add[(256 + p) * 256 + c], acc);
    }
    prop_add[b * 256 + c] = acc;
}

// ---------------------------------------------------------------------------
__global__ void wf_kernel(const float* __restrict__ W3, const float* __restrict__ b3,
                          const float* __restrict__ W_out, const float* __restrict__ b_out,
                          float* __restrict__ Wf, float* __restrict__ bf)
{
    const int c = threadIdx.x;
    float acc[NET] = {0.f, 0.f, 0.f, 0.f, 0.f};
    for (int j = 0; j < 512; ++j) {
        const float wv = W3[c * 512 + j];
        #pragma unroll
        for (int t = 0; t < NET; ++t) acc[t] = fmaf(wv, W_out[j * NET + t], acc[t]);
    }
    #pragma unroll
    for (int t = 0; t < NET; ++t) Wf[c * NET + t] = acc[t];
    if (c == 0) {
        float s[NET];
        for (int t = 0; t < NET; ++t) s[t] = b_out[t];
        for (int j = 0; j < 512; ++j) {
            const float bj = b3[j];
            for (int t = 0; t < NET; ++t) s[t] = fmaf(bj, W_out[j * NET + t], s[t]);
        }
        for (int t = 0; t < NET; ++t) bf[t] = s[t];
    }
}

// ---------------------------------------------------------------------------
// Fused pair MLP + CE with MFMA: 64 pairs/block.
// h1 = relu(A1[s]+A2[d]+b1) -> bf16 LDS [64][264]; h2 = relu(h1@W2+b2) via MFMA;
// logits = h2@Wf + bf; loss accumulation.
// ---------------------------------------------------------------------------
__global__ __launch_bounds__(256, 2) void pair_mfma(
    const float* __restrict__ A1t, const float* __restrict__ A2t,
    const float* __restrict__ b1, const unsigned short* __restrict__ W2T,
    const float* __restrict__ b2, const float* __restrict__ Wf,
    const float* __restrict__ bfp,
    const int* __restrict__ sel_b, const int* __restrict__ sel_i,
    const int* __restrict__ sel_j, const int* __restrict__ golden,
    float* __restrict__ out)
{
    __shared__ __align__(16) unsigned short H1s[64 * 264];  // stride 264 shorts
    __shared__ __align__(16) unsigned short Bs[256 * 40];
    __shared__ int sidx[64], didx[64], gold[64];
    __shared__ float red[16];

    const int tid = threadIdx.x;
    const int e0 = blockIdx.x * 64;
    if (tid < 64) {
        const int e = e0 + tid;
        const int b = sel_b[e];
        sidx[tid] = b * N_PER_B + sel_i[e];
        didx[tid] = b * N_PER_B + sel_j[e];
        gold[tid] = golden[e];
    }
    __syncthreads();

    const float b1c = b1[tid];
    for (int p = 0; p < 64; ++p) {
        const float v = A1t[(size_t)sidx[p] * 256 + tid]
                      + A2t[(size_t)didx[p] * 256 + tid] + b1c;
        H1s[p * 264 + tid] = f2bf(fmaxf(v, 0.f));
    }

    const int w = tid >> 6;
    const int lane = tid & 63;
    const int q = lane >> 4;
    const int tx = lane & 15;

    f32x4 acc[16];
    #pragma unroll
    for (int c = 0; c < 16; ++c) acc[c] = (f32x4)0.f;

    for (int k0 = 0; k0 < 256; k0 += 32) {
        {   // stage W2T chunk: 256 n x 32 k
            const int4* bp = (const int4*)(W2T + (size_t)tid * 256 + k0);
            const int4 x0 = bp[0], x1 = bp[1], x2 = bp[2], x3 = bp[3];
            int4* dp = (int4*)&Bs[tid * 40];
            dp[0] = x0; dp[1] = x1; dp[2] = x2; dp[3] = x3;
        }
        __syncthreads();
        const short8 af = *(const short8*)&H1s[(w * 16 + tx) * 264 + k0 + q * 8];
        #pragma unroll
        for (int c = 0; c < 16; ++c) {
            const short8 bf = *(const short8*)&Bs[(c * 16 + tx) * 40 + q * 8];
            acc[c] = __builtin_amdgcn_mfma_f32_16x16x32_bf16(af, bf, acc[c], 0, 0, 0);
        }
        __syncthreads();
    }

    // epilogue: bias+relu, fold through Wf, reduce over the 16 col-lanes
    float pl[4][NET];
    #pragma unroll
    for (int r = 0; r < 4; ++r)
        #pragma unroll
        for (int t = 0; t < NET; ++t) pl[r][t] = 0.f;

    #pragma unroll
    for (int c = 0; c < 16; ++c) {
        const int col = c * 16 + tx;
        const float b2v = b2[col];
        float wfv[NET];
        #pragma unroll
        for (int t = 0; t < NET; ++t) wfv[t] = Wf[col * NET + t];
        #pragma unroll
        for (int r = 0; r < 4; ++r) {
            const float v = fmaxf(acc[c][r] + b2v, 0.f);
            #pragma unroll
            for (int t = 0; t < NET; ++t) pl[r][t] = fmaf(v, wfv[t], pl[r][t]);
        }
    }
    #pragma unroll
    for (int r = 0; r < 4; ++r)
        #pragma unroll
        for (int t = 0; t < NET; ++t) {
            float v = pl[r][t];
            for (int off = 1; off < 16; off <<= 1) v += __shfl_xor(v, off, 16);
            pl[r][t] = v;
        }

    if (tx == 0) {
        float lsum = 0.f;
        #pragma unroll
        for (int r = 0; r < 4; ++r) {
            const int p = w * 16 + q * 4 + r;
            float lg[NET];
            #pragma unroll
            for (int t = 0; t < NET; ++t) lg[t] = pl[r][t] + bfp[t];
            float mx = lg[0];
            #pragma unroll
            for (int t = 1; t < NET; ++t) mx = fmaxf(mx, lg[t]);
            float s = 0.f;
            #pragma unroll
            for (int t = 0; t < NET; ++t) s += expf(lg[t] - mx);
            lsum += mx + logf(s) - lg[gold[p]];
        }
        red[w * 4 + q] = lsum;
    }
    __syncthreads();
    if (tid == 0) {
        float s = 0.f;
        #pragma unroll
        for (int i = 0; i < 16; ++i) s += red[i];
        atomicAdd(out, s * (1.0f / NSEL));
    }
}

// ---------------------------------------------------------------------------
extern "C" void kernel_launch(void* const* d_in, const int* in_sizes, int n_in,
                              void* d_out, int out_size, void* d_ws, size_t ws_size,
                              hipStream_t stream) {
    (void)in_sizes; (void)n_in; (void)out_size; (void)ws_size;
    const float* x      = (const float*)d_in[0];
    const int*   eidx   = (const int*)d_in[1];
    const float* eattr  = (const float*)d_in[2];
    const float* props  = (const float*)d_in[3];
    const int*   sel_b  = (const int*)d_in[4];
    const int*   sel_i  = (const int*)d_in[5];
    const int*   sel_j  = (const int*)d_in[6];
    const int*   golden = (const int*)d_in[7];
    const float* W_prop = (const float*)d_in[8];
    const float* b_prop = (const float*)d_in[9];
    const float* W_in   = (const float*)d_in[10];
    const float* b_in   = (const float*)d_in[11];
    const float* W_msg  = (const float*)d_in[12];
    const float* b_msg  = (const float*)d_in[13];
    const float* W_upd  = (const float*)d_in[14];
    const float* b_upd  = (const float*)d_in[15];
    const float* W_add  = (const float*)d_in[16];
    const float* b_add  = (const float*)d_in[17];
    const float* W1     = (const float*)d_in[18];
    const float* b1     = (const float*)d_in[19];
    const float* W2     = (const float*)d_in[20];
    const float* b2     = (const float*)d_in[21];
    const float* W3     = (const float*)d_in[22];
    const float* b3     = (const float*)d_in[23];
    const float* W_out  = (const float*)d_in[24];
    const float* b_out  = (const float*)d_in[25];

    float* ws = (float*)d_ws;
    const size_t SEG = (size_t)BN * 256;
    float* bufA = ws;                 // h (even)
    float* bufB = ws + SEG;           // h (odd) -> A2
    float* bufC = ws + 2 * SEG;       // P -> embg
    float* bufD = ws + 3 * SEG;       // agg -> A1
    float* prop_add = ws + 4 * SEG;   // [64,256]
    float* Wf = prop_add + 64 * 256;
    float* bf = Wf + 256 * NET;
    unsigned short* wbf = (unsigned short*)(bf + 16);  // bf16 weight region
    unsigned short* W_inT  = wbf;                       // [256][192]
    unsigned short* Wm_hT  = wbf + 49152;               // [256][256]
    unsigned short* Wu_aT  = Wm_hT + 65536;
    unsigned short* Wu_bT  = Wu_aT + 65536;
    unsigned short* W_addT = Wu_bT + 65536;
    unsigned short* W1aT   = W_addT + 65536;
    unsigned short* W1bT   = W1aT + 65536;
    unsigned short* W2T    = W1bT + 65536;

    conv_weights<<<dim3(16, 8), 256, 0, stream>>>(W_in, W_msg, W_upd, W_add, W1, W2, wbf);

    dim3 ggrid(2, 64);   // 2 col-halves x 64 row-tiles

    // h = relu(x @ W_in + b_in)
    gemm_mfma<<<ggrid, 256, 0, stream>>>(x, W_inT, 192, nullptr, nullptr, b_in, nullptr, bufA, 1);

    float* hcur = bufA; float* halt = bufB;
    for (int t = 0; t < 4; ++t) {
        gemm_mfma<<<ggrid, 256, 0, stream>>>(hcur, Wm_hT, 256, nullptr, nullptr, nullptr, nullptr, bufC, 0);
        hipMemsetAsync(bufD, 0, SEG * sizeof(float), stream);
        edge_kernel<<<NE / 4, 256, 0, stream>>>(bufC, eidx, eattr, W_msg + 256 * 256, b_msg, bufD);
        gemm_mfma<<<ggrid, 256, 0, stream>>>(hcur, Wu_aT, 256, bufD, Wu_bT, b_upd, nullptr, halt, 1);
        float* tmp = hcur; hcur = halt; halt = tmp;
    }

    prop_kernel<<<N_PER_B, 256, 0, stream>>>(props, W_prop, b_prop, W_add, b_add, prop_add);
    gemm_mfma<<<ggrid, 256, 0, stream>>>(hcur, W_addT, 256, nullptr, nullptr, nullptr, prop_add, bufC, 0);
    gemm_mfma<<<ggrid, 256, 0, stream>>>(bufC, W1aT, 256, nullptr, nullptr, nullptr, nullptr, bufD, 0);
    gemm_mfma<<<ggrid, 256, 0, stream>>>(bufC, W1bT, 256, nullptr, nullptr, nullptr, nullptr, halt, 0);
    wf_kernel<<<1, 256, 0, stream>>>(W3, b3, W_out, b_out, Wf, bf);

    hipMemsetAsync(d_out, 0, sizeof(float), stream);
    pair_mfma<<<NSEL / 64, 256, 0, stream>>>(bufD, halt, b1, W2T, b2, Wf, bf,
                                             sel_b, sel_i, sel_j, golden, (float*)d_out);
}

// Round 3
// 379.517 us; speedup vs baseline: 2.4173x; 1.6284x over previous
//
#include <hip/hip_runtime.h>
#include <math.h>

#define HD 256
#define BN 4096
#define N_PER_B 64
#define NE 16384
#define NSEL 65536
#define NET 5
#define PD 64

typedef float f32x4 __attribute__((ext_vector_type(4)));
typedef short short8 __attribute__((ext_vector_type(8)));

__device__ inline unsigned short f2bf(float f) {
    unsigned int u = __builtin_bit_cast(unsigned int, f);
    u += 0x7fff + ((u >> 16) & 1);          // round-to-nearest-even
    return (unsigned short)(u >> 16);
}

// ---------------------------------------------------------------------------
// Weight convert + transpose: src fp32 [K][256] -> dst bf16 [256][K]
// ---------------------------------------------------------------------------
__global__ __launch_bounds__(256) void conv_weights(
    const float* __restrict__ W_in, const float* __restrict__ W_msg,
    const float* __restrict__ W_upd, const float* __restrict__ W_add,
    const float* __restrict__ W1, const float* __restrict__ W2,
    unsigned short* __restrict__ dstbase)
{
    __shared__ float s[64][65];
    const int wsel = blockIdx.y;
    const float* src; unsigned short* dst; int K = 256;
    switch (wsel) {
        case 0: src = W_in;              dst = dstbase;                      K = 192; break;
        case 1: src = W_msg;             dst = dstbase + 49152;              break;
        case 2: src = W_upd;             dst = dstbase + 49152 + 65536;      break;
        case 3: src = W_upd + 256 * 256; dst = dstbase + 49152 + 2 * 65536;  break;
        case 4: src = W_add;             dst = dstbase + 49152 + 3 * 65536;  break;
        case 5: src = W1;                dst = dstbase + 49152 + 4 * 65536;  break;
        case 6: src = W1 + 256 * 256;    dst = dstbase + 49152 + 5 * 65536;  break;
        default: src = W2;               dst = dstbase + 49152 + 6 * 65536;  break;
    }
    const int k0 = (blockIdx.x >> 2) * 64;
    const int n0 = (blockIdx.x & 3) * 64;
    if (k0 >= K) return;
    const int tn = threadIdx.x & 63;
    const int tg = threadIdx.x >> 6;
    #pragma unroll
    for (int i = 0; i < 16; ++i) {
        const int kk = tg * 16 + i;
        s[kk][tn] = src[(size_t)(k0 + kk) * 256 + n0 + tn];
    }
    __syncthreads();
    #pragma unroll
    for (int i = 0; i < 16; ++i) {
        const int nn = tg * 16 + i;
        dst[(size_t)(n0 + nn) * K + k0 + tn] = f2bf(s[tn][nn]);
    }
}

// ---------------------------------------------------------------------------
// MFMA node GEMM: C[4096,256] = act( A0@W0 (+ A1@W1) + bias + rowadd[batch] )
// ---------------------------------------------------------------------------
__global__ __launch_bounds__(256, 2) void gemm_mfma(
    const float* __restrict__ A0, const unsigned short* __restrict__ WT0, int K0,
    const float* __restrict__ A1, const unsigned short* __restrict__ WT1,
    const float* __restrict__ bias, const float* __restrict__ rowadd,
    float* __restrict__ C, int relu)
{
    __shared__ __align__(16) unsigned short As[64 * 40];
    __shared__ __align__(16) unsigned short Bs[128 * 40];
    const int tid = threadIdx.x;
    const int w = tid >> 6;
    const int lane = tid & 63;
    const int q = lane >> 4;
    const int tx = lane & 15;
    const int row0 = blockIdx.y * 64;
    const int col0 = blockIdx.x * 128;

    f32x4 acc[8];
    #pragma unroll
    for (int c = 0; c < 8; ++c) acc[c] = (f32x4)0.f;

    for (int pass = 0; pass < 2; ++pass) {
        const float* A = pass ? A1 : A0;
        const unsigned short* WT = pass ? WT1 : WT0;
        const int K = pass ? 256 : K0;
        if (A == nullptr) continue;
        for (int k0 = 0; k0 < K; k0 += 32) {
            {   // stage A: 64 rows x 32 k, fp32 -> bf16
                const int r = tid >> 2;
                const int kq = (tid & 3) * 8;
                const float* ap = A + (size_t)(row0 + r) * K + k0 + kq;
                const float4 v0 = *(const float4*)ap;
                const float4 v1 = *(const float4*)(ap + 4);
                int4 pk;
                pk.x = f2bf(v0.x) | (f2bf(v0.y) << 16);
                pk.y = f2bf(v0.z) | (f2bf(v0.w) << 16);
                pk.z = f2bf(v1.x) | (f2bf(v1.y) << 16);
                pk.w = f2bf(v1.z) | (f2bf(v1.w) << 16);
                *(int4*)&As[r * 40 + kq] = pk;
            }
            {   // stage B: 128 cols x 32 k (bf16)
                const int n = tid >> 1;
                const int kq = (tid & 1) * 16;
                const int4* bp = (const int4*)(WT + (size_t)(col0 + n) * K + k0 + kq);
                const int4 b0 = bp[0];
                const int4 b1 = bp[1];
                *(int4*)&Bs[n * 40 + kq] = b0;
                *(int4*)&Bs[n * 40 + kq + 8] = b1;
            }
            __syncthreads();
            const short8 af = *(const short8*)&As[(w * 16 + tx) * 40 + q * 8];
            #pragma unroll
            for (int c = 0; c < 8; ++c) {
                const short8 bfr = *(const short8*)&Bs[(c * 16 + tx) * 40 + q * 8];
                acc[c] = __builtin_amdgcn_mfma_f32_16x16x32_bf16(af, bfr, acc[c], 0, 0, 0);
            }
            __syncthreads();
        }
    }

    const int bidx = row0 >> 6;
    #pragma unroll
    for (int c = 0; c < 8; ++c) {
        const int col = col0 + c * 16 + tx;
        float badd = bias ? bias[col] : 0.f;
        if (rowadd) badd += rowadd[bidx * 256 + col];
        #pragma unroll
        for (int r = 0; r < 4; ++r) {
            const int m = row0 + w * 16 + q * 4 + r;
            float v = acc[c][r] + badd;
            if (relu) v = fmaxf(v, 0.f);
            C[(size_t)m * 256 + col] = v;
        }
    }
}

// ---------------------------------------------------------------------------
// CSR build (dst -> edge ids): histogram, scan, scatter
// ---------------------------------------------------------------------------
__global__ __launch_bounds__(256) void csr_hist(const int* __restrict__ eidx,
                                                int* __restrict__ deg)
{
    const int e = blockIdx.x * 256 + threadIdx.x;
    atomicAdd(&deg[eidx[NE + e]], 1);
}

__global__ __launch_bounds__(256) void csr_scan(const int* __restrict__ deg,
                                                int* __restrict__ row_start,
                                                int* __restrict__ cursor)
{
    __shared__ int sums[256];
    const int tid = threadIdx.x;
    const int base = tid * 16;
    int local[16];
    int s = 0;
    #pragma unroll
    for (int i = 0; i < 16; ++i) { local[i] = s; s += deg[base + i]; }
    sums[tid] = s;
    __syncthreads();
    for (int off = 1; off < 256; off <<= 1) {
        const int v = sums[tid];
        const int add = (tid >= off) ? sums[tid - off] : 0;
        __syncthreads();
        sums[tid] = v + add;
        __syncthreads();
    }
    const int offset = (tid == 0) ? 0 : sums[tid - 1];
    #pragma unroll
    for (int i = 0; i < 16; ++i) {
        const int v = offset + local[i];
        row_start[base + i] = v;
        cursor[base + i] = v;
    }
    if (tid == 255) row_start[4096] = NE;
}

__global__ __launch_bounds__(256) void csr_scatter(const int* __restrict__ eidx,
                                                   int* __restrict__ cursor,
                                                   int* __restrict__ eids)
{
    const int e = blockIdx.x * 256 + threadIdx.x;
    const int pos = atomicAdd(&cursor[eidx[NE + e]], 1);
    eids[pos] = e;
}

// ---------------------------------------------------------------------------
// Fused message + aggregation (gather form, no atomics):
// agg[n] = sum_{e: dst=n} relu(P[src_e] + eattr_e @ Wme + b_msg)
// one 64-lane wave per node, 4 cols/lane
// ---------------------------------------------------------------------------
__global__ __launch_bounds__(256) void agg_kernel(
    const float* __restrict__ P, const int* __restrict__ eidx,
    const float* __restrict__ eattr, const float* __restrict__ Wme,
    const float* __restrict__ bmsg, const int* __restrict__ row_start,
    const int* __restrict__ eids, float* __restrict__ agg)
{
    const int n = blockIdx.x * 4 + (threadIdx.x >> 6);
    const int lane = threadIdx.x & 63;
    const int c = lane * 4;
    const float4 bm = *(const float4*)(bmsg + c);
    const float4 w0 = *(const float4*)(Wme + 0 * 256 + c);
    const float4 w1 = *(const float4*)(Wme + 1 * 256 + c);
    const float4 w2 = *(const float4*)(Wme + 2 * 256 + c);
    const float4 w3 = *(const float4*)(Wme + 3 * 256 + c);
    const float4 w4 = *(const float4*)(Wme + 4 * 256 + c);
    const int beg = row_start[n];
    const int end = row_start[n + 1];
    float ax = 0.f, ay = 0.f, az = 0.f, aw = 0.f;
    for (int idx = beg; idx < end; ++idx) {
        const int e = eids[idx];
        const int src = eidx[e];
        const float a0 = eattr[e * NET + 0];
        const float a1 = eattr[e * NET + 1];
        const float a2 = eattr[e * NET + 2];
        const float a3 = eattr[e * NET + 3];
        const float a4 = eattr[e * NET + 4];
        const float4 p = *(const float4*)(P + (size_t)src * 256 + c);
        float vx = p.x + bm.x, vy = p.y + bm.y, vz = p.z + bm.z, vw = p.w + bm.w;
        vx = fmaf(a0, w0.x, vx); vy = fmaf(a0, w0.y, vy); vz = fmaf(a0, w0.z, vz); vw = fmaf(a0, w0.w, vw);
        vx = fmaf(a1, w1.x, vx); vy = fmaf(a1, w1.y, vy); vz = fmaf(a1, w1.z, vz); vw = fmaf(a1, w1.w, vw);
        vx = fmaf(a2, w2.x, vx); vy = fmaf(a2, w2.y, vy); vz = fmaf(a2, w2.z, vz); vw = fmaf(a2, w2.w, vw);
        vx = fmaf(a3, w3.x, vx); vy = fmaf(a3, w3.y, vy); vz = fmaf(a3, w3.z, vz); vw = fmaf(a3, w3.w, vw);
        vx = fmaf(a4, w4.x, vx); vy = fmaf(a4, w4.y, vy); vz = fmaf(a4, w4.z, vz); vw = fmaf(a4, w4.w, vw);
        ax += fmaxf(vx, 0.f); ay += fmaxf(vy, 0.f);
        az += fmaxf(vz, 0.f); aw += fmaxf(vw, 0.f);
    }
    float4 o; o.x = ax; o.y = ay; o.z = az; o.w = aw;
    *(float4*)(agg + (size_t)n * 256 + c) = o;
}

// ---------------------------------------------------------------------------
__global__ void prop_kernel(const float* __restrict__ props, const float* __restrict__ W_prop,
                            const float* __restrict__ b_prop, const float* __restrict__ W_add,
                            const float* __restrict__ b_add, float* __restrict__ prop_add)
{
    const int b = blockIdx.x;
    const int c = threadIdx.x;
    const float pv = props[b];
    float acc = b_add[c];
    for (int p = 0; p < PD; ++p) {
        const float e = fmaf(pv, W_prop[p], b_prop[p]);
        acc = fmaf(e, W_add[(256 + p) * 256 + c], acc);
    }
    prop_add[b * 256 + c] = acc;
}

// ---------------------------------------------------------------------------
// Wf[c][t] = sum_j W3[c][j]*W_out[j][t] (blocks 0..255);  bf (block 256)
// ---------------------------------------------------------------------------
__global__ __launch_bounds__(256) void wf_kernel(
    const float* __restrict__ W3, const float* __restrict__ b3,
    const float* __restrict__ W_out, const float* __restrict__ b_out,
    float* __restrict__ Wf, float* __restrict__ bf)
{
    __shared__ float part[4][NET];
    const int tid = threadIdx.x;
    const int blk = blockIdx.x;
    float acc[NET] = {0.f, 0.f, 0.f, 0.f, 0.f};
    if (blk < 256) {
        #pragma unroll
        for (int rep = 0; rep < 2; ++rep) {
            const int j = rep * 256 + tid;
            const float wv = W3[(size_t)blk * 512 + j];
            #pragma unroll
            for (int t = 0; t < NET; ++t) acc[t] = fmaf(wv, W_out[j * NET + t], acc[t]);
        }
    } else {
        #pragma unroll
        for (int rep = 0; rep < 2; ++rep) {
            const int j = rep * 256 + tid;
            const float wv = b3[j];
            #pragma unroll
            for (int t = 0; t < NET; ++t) acc[t] = fmaf(wv, W_out[j * NET + t], acc[t]);
        }
    }
    #pragma unroll
    for (int t = 0; t < NET; ++t)
        for (int off = 32; off >= 1; off >>= 1) acc[t] += __shfl_down(acc[t], off);
    if ((tid & 63) == 0) {
        #pragma unroll
        for (int t = 0; t < NET; ++t) part[tid >> 6][t] = acc[t];
    }
    __syncthreads();
    if (tid == 0) {
        float s[NET];
        #pragma unroll
        for (int t = 0; t < NET; ++t)
            s[t] = part[0][t] + part[1][t] + part[2][t] + part[3][t];
        if (blk < 256) {
            #pragma unroll
            for (int t = 0; t < NET; ++t) Wf[blk * NET + t] = s[t];
        } else {
            #pragma unroll
            for (int t = 0; t < NET; ++t) bf[t] = s[t] + b_out[t];
        }
    }
}

// ---------------------------------------------------------------------------
// Fused pair MLP + CE with MFMA: 64 pairs/block.
// ---------------------------------------------------------------------------
__global__ __launch_bounds__(256, 2) void pair_mfma(
    const float* __restrict__ A1t, const float* __restrict__ A2t,
    const float* __restrict__ b1, const unsigned short* __restrict__ W2T,
    const float* __restrict__ b2, const float* __restrict__ Wf,
    const float* __restrict__ bfp,
    const int* __restrict__ sel_b, const int* __restrict__ sel_i,
    const int* __restrict__ sel_j, const int* __restrict__ golden,
    float* __restrict__ out)
{
    __shared__ __align__(16) unsigned short H1s[64 * 264];
    __shared__ __align__(16) unsigned short Bs[256 * 40];
    __shared__ int sidx[64], didx[64], gold[64];
    __shared__ float red[16];

    const int tid = threadIdx.x;
    const int e0 = blockIdx.x * 64;
    if (tid < 64) {
        const int e = e0 + tid;
        const int b = sel_b[e];
        sidx[tid] = b * N_PER_B + sel_i[e];
        didx[tid] = b * N_PER_B + sel_j[e];
        gold[tid] = golden[e];
    }
    __syncthreads();

    const float b1c = b1[tid];
    for (int p = 0; p < 64; ++p) {
        const float v = A1t[(size_t)sidx[p] * 256 + tid]
                      + A2t[(size_t)didx[p] * 256 + tid] + b1c;
        H1s[p * 264 + tid] = f2bf(fmaxf(v, 0.f));
    }

    const int w = tid >> 6;
    const int lane = tid & 63;
    const int q = lane >> 4;
    const int tx = lane & 15;

    f32x4 acc[16];
    #pragma unroll
    for (int c = 0; c < 16; ++c) acc[c] = (f32x4)0.f;

    for (int k0 = 0; k0 < 256; k0 += 32) {
        {
            const int4* bp = (const int4*)(W2T + (size_t)tid * 256 + k0);
            const int4 x0 = bp[0], x1 = bp[1], x2 = bp[2], x3 = bp[3];
            int4* dp = (int4*)&Bs[tid * 40];
            dp[0] = x0; dp[1] = x1; dp[2] = x2; dp[3] = x3;
        }
        __syncthreads();
        const short8 af = *(const short8*)&H1s[(w * 16 + tx) * 264 + k0 + q * 8];
        #pragma unroll
        for (int c = 0; c < 16; ++c) {
            const short8 bfr = *(const short8*)&Bs[(c * 16 + tx) * 40 + q * 8];
            acc[c] = __builtin_amdgcn_mfma_f32_16x16x32_bf16(af, bfr, acc[c], 0, 0, 0);
        }
        __syncthreads();
    }

    float pl[4][NET];
    #pragma unroll
    for (int r = 0; r < 4; ++r)
        #pragma unroll
        for (int t = 0; t < NET; ++t) pl[r][t] = 0.f;

    #pragma unroll
    for (int c = 0; c < 16; ++c) {
        const int col = c * 16 + tx;
        const float b2v = b2[col];
        float wfv[NET];
        #pragma unroll
        for (int t = 0; t < NET; ++t) wfv[t] = Wf[col * NET + t];
        #pragma unroll
        for (int r = 0; r < 4; ++r) {
            const float v = fmaxf(acc[c][r] + b2v, 0.f);
            #pragma unroll
            for (int t = 0; t < NET; ++t) pl[r][t] = fmaf(v, wfv[t], pl[r][t]);
        }
    }
    #pragma unroll
    for (int r = 0; r < 4; ++r)
        #pragma unroll
        for (int t = 0; t < NET; ++t) {
            float v = pl[r][t];
            for (int off = 1; off < 16; off <<= 1) v += __shfl_xor(v, off, 16);
            pl[r][t] = v;
        }

    if (tx == 0) {
        float lsum = 0.f;
        #pragma unroll
        for (int r = 0; r < 4; ++r) {
            const int p = w * 16 + q * 4 + r;
            float lg[NET];
            #pragma unroll
            for (int t = 0; t < NET; ++t) lg[t] = pl[r][t] + bfp[t];
            float mx = lg[0];
            #pragma unroll
            for (int t = 1; t < NET; ++t) mx = fmaxf(mx, lg[t]);
            float s = 0.f;
            #pragma unroll
            for (int t = 0; t < NET; ++t) s += expf(lg[t] - mx);
            lsum += mx + logf(s) - lg[gold[p]];
        }
        red[w * 4 + q] = lsum;
    }
    __syncthreads();
    if (tid == 0) {
        float s = 0.f;
        #pragma unroll
        for (int i = 0; i < 16; ++i) s += red[i];
        atomicAdd(out, s * (1.0f / NSEL));
    }
}

// ---------------------------------------------------------------------------
extern "C" void kernel_launch(void* const* d_in, const int* in_sizes, int n_in,
                              void* d_out, int out_size, void* d_ws, size_t ws_size,
                              hipStream_t stream) {
    (void)in_sizes; (void)n_in; (void)out_size; (void)ws_size;
    const float* x      = (const float*)d_in[0];
    const int*   eidx   = (const int*)d_in[1];
    const float* eattr  = (const float*)d_in[2];
    const float* props  = (const float*)d_in[3];
    const int*   sel_b  = (const int*)d_in[4];
    const int*   sel_i  = (const int*)d_in[5];
    const int*   sel_j  = (const int*)d_in[6];
    const int*   golden = (const int*)d_in[7];
    const float* W_prop = (const float*)d_in[8];
    const float* b_prop = (const float*)d_in[9];
    const float* W_in   = (const float*)d_in[10];
    const float* b_in   = (const float*)d_in[11];
    const float* W_msg  = (const float*)d_in[12];
    const float* b_msg  = (const float*)d_in[13];
    const float* W_upd  = (const float*)d_in[14];
    const float* b_upd  = (const float*)d_in[15];
    const float* W_add  = (const float*)d_in[16];
    const float* b_add  = (const float*)d_in[17];
    const float* W1     = (const float*)d_in[18];
    const float* b1     = (const float*)d_in[19];
    const float* W2     = (const float*)d_in[20];
    const float* b2     = (const float*)d_in[21];
    const float* W3     = (const float*)d_in[22];
    const float* b3     = (const float*)d_in[23];
    const float* W_out  = (const float*)d_in[24];
    const float* b_out  = (const float*)d_in[25];

    float* ws = (float*)d_ws;
    const size_t SEG = (size_t)BN * 256;
    float* bufA = ws;                 // h (even)
    float* bufB = ws + SEG;           // h (odd) -> A2
    float* bufC = ws + 2 * SEG;       // P -> embg
    float* bufD = ws + 3 * SEG;       // agg -> A1
    float* prop_add = ws + 4 * SEG;   // [64,256]
    float* Wf = prop_add + 64 * 256;
    float* bf = Wf + 256 * NET;
    unsigned short* wbf = (unsigned short*)(bf + 16);   // bf16 weights
    unsigned short* W_inT  = wbf;                        // [256][192]
    unsigned short* Wm_hT  = wbf + 49152;                // [256][256]
    unsigned short* Wu_aT  = Wm_hT + 65536;
    unsigned short* Wu_bT  = Wu_aT + 65536;
    unsigned short* W_addT = Wu_bT + 65536;
    unsigned short* W1aT   = W_addT + 65536;
    unsigned short* W1bT   = W1aT + 65536;
    unsigned short* W2T    = W1bT + 65536;
    int* ipt = (int*)(W2T + 65536);
    int* deg       = ipt;             // [4096]
    int* row_start = ipt + 4096;      // [4097]
    int* cursor    = ipt + 4096 + 4112;
    int* eids      = cursor + 4096;   // [16384]

    conv_weights<<<dim3(16, 8), 256, 0, stream>>>(W_in, W_msg, W_upd, W_add, W1, W2, wbf);

    // CSR build (dst -> edges), once per launch
    hipMemsetAsync(deg, 0, 4096 * sizeof(int), stream);
    csr_hist<<<NE / 256, 256, 0, stream>>>(eidx, deg);
    csr_scan<<<1, 256, 0, stream>>>(deg, row_start, cursor);
    csr_scatter<<<NE / 256, 256, 0, stream>>>(eidx, cursor, eids);

    dim3 ggrid(2, 64);

    gemm_mfma<<<ggrid, 256, 0, stream>>>(x, W_inT, 192, nullptr, nullptr, b_in, nullptr, bufA, 1);

    float* hcur = bufA; float* halt = bufB;
    for (int t = 0; t < 4; ++t) {
        gemm_mfma<<<ggrid, 256, 0, stream>>>(hcur, Wm_hT, 256, nullptr, nullptr, nullptr, nullptr, bufC, 0);
        agg_kernel<<<BN / 4, 256, 0, stream>>>(bufC, eidx, eattr, W_msg + 256 * 256, b_msg,
                                               row_start, eids, bufD);
        gemm_mfma<<<ggrid, 256, 0, stream>>>(hcur, Wu_aT, 256, bufD, Wu_bT, b_upd, nullptr, halt, 1);
        float* tmp = hcur; hcur = halt; halt = tmp;
    }

    prop_kernel<<<N_PER_B, 256, 0, stream>>>(props, W_prop, b_prop, W_add, b_add, prop_add);
    gemm_mfma<<<ggrid, 256, 0, stream>>>(hcur, W_addT, 256, nullptr, nullptr, nullptr, prop_add, bufC, 0);
    gemm_mfma<<<ggrid, 256, 0, stream>>>(bufC, W1aT, 256, nullptr, nullptr, nullptr, nullptr, bufD, 0);
    gemm_mfma<<<ggrid, 256, 0, stream>>>(bufC, W1bT, 256, nullptr, nullptr, nullptr, nullptr, halt, 0);
    wf_kernel<<<257, 256, 0, stream>>>(W3, b3, W_out, b_out, Wf, bf);

    hipMemsetAsync(d_out, 0, sizeof(float), stream);
    pair_mfma<<<NSEL / 64, 256, 0, stream>>>(bufD, halt, b1, W2T, b2, Wf, bf,
                                             sel_b, sel_i, sel_j, golden, (float*)d_out);
}

// Round 4
// 362.244 us; speedup vs baseline: 2.5326x; 1.0477x over previous
//
#include <hip/hip_runtime.h>
#include <math.h>

#define HD 256
#define BN 4096
#define N_PER_B 64
#define NE 16384
#define NSEL 65536
#define NET 5
#define PD 64
#define HSTR 260   // LDS row stride (shorts) for A-fragment tiles: 130 dwords == 2 mod 32 -> 2-way (free)

typedef float f32x4 __attribute__((ext_vector_type(4)));
typedef short short8 __attribute__((ext_vector_type(8)));
typedef short short4v __attribute__((ext_vector_type(4)));

__device__ __forceinline__ unsigned short f2bf(float f) {
    unsigned int u = __builtin_bit_cast(unsigned int, f);
    u += 0x7fff + ((u >> 16) & 1);          // round-to-nearest-even
    return (unsigned short)(u >> 16);
}
__device__ __forceinline__ float b2f(unsigned short u) {
    return __builtin_bit_cast(float, ((unsigned int)u) << 16);
}
// 16-byte fragment from 8-byte-aligned LDS (stride HSTR keeps banks 2-way)
__device__ __forceinline__ short8 ld_frag(const unsigned short* p) {
    const short4v lo = *(const short4v*)(p);
    const short4v hi = *(const short4v*)(p + 4);
    return __builtin_shufflevector(lo, hi, 0, 1, 2, 3, 4, 5, 6, 7);
}

// ---------------------------------------------------------------------------
// Weight convert + transpose: src fp32 [K][256] -> dst bf16 [256][K]
// ---------------------------------------------------------------------------
__global__ __launch_bounds__(256) void conv_weights(
    const float* __restrict__ W_in, const float* __restrict__ W_msg,
    const float* __restrict__ W_upd, const float* __restrict__ W_add,
    const float* __restrict__ W1, const float* __restrict__ W2,
    unsigned short* __restrict__ dstbase)
{
    __shared__ float s[64][65];
    const int wsel = blockIdx.y;
    const float* src; unsigned short* dst; int K = 256;
    switch (wsel) {
        case 0: src = W_in;              dst = dstbase;                      K = 192; break;
        case 1: src = W_msg;             dst = dstbase + 49152;              break;
        case 2: src = W_upd;             dst = dstbase + 49152 + 65536;      break;
        case 3: src = W_upd + 256 * 256; dst = dstbase + 49152 + 2 * 65536;  break;
        case 4: src = W_add;             dst = dstbase + 49152 + 3 * 65536;  break;
        case 5: src = W1;                dst = dstbase + 49152 + 4 * 65536;  break;
        case 6: src = W1 + 256 * 256;    dst = dstbase + 49152 + 5 * 65536;  break;
        default: src = W2;               dst = dstbase + 49152 + 6 * 65536;  break;
    }
    const int k0 = (blockIdx.x >> 2) * 64;
    const int n0 = (blockIdx.x & 3) * 64;
    if (k0 >= K) return;
    const int tn = threadIdx.x & 63;
    const int tg = threadIdx.x >> 6;
    #pragma unroll
    for (int i = 0; i < 16; ++i) {
        const int kk = tg * 16 + i;
        s[kk][tn] = src[(size_t)(k0 + kk) * 256 + n0 + tn];
    }
    __syncthreads();
    #pragma unroll
    for (int i = 0; i < 16; ++i) {
        const int nn = tg * 16 + i;
        dst[(size_t)(n0 + nn) * K + k0 + tn] = f2bf(s[tn][nn]);
    }
}

// ---------------------------------------------------------------------------
// CSR build (dst -> edge ids)
// ---------------------------------------------------------------------------
__global__ __launch_bounds__(256) void csr_hist(const int* __restrict__ eidx,
                                                int* __restrict__ deg)
{
    const int e = blockIdx.x * 256 + threadIdx.x;
    atomicAdd(&deg[eidx[NE + e]], 1);
}

__global__ __launch_bounds__(256) void csr_scan(const int* __restrict__ deg,
                                                int* __restrict__ row_start,
                                                int* __restrict__ cursor)
{
    __shared__ int sums[256];
    const int tid = threadIdx.x;
    const int base = tid * 16;
    int local[16];
    int s = 0;
    #pragma unroll
    for (int i = 0; i < 16; ++i) { local[i] = s; s += deg[base + i]; }
    sums[tid] = s;
    __syncthreads();
    for (int off = 1; off < 256; off <<= 1) {
        const int v = sums[tid];
        const int add = (tid >= off) ? sums[tid - off] : 0;
        __syncthreads();
        sums[tid] = v + add;
        __syncthreads();
    }
    const int offset = (tid == 0) ? 0 : sums[tid - 1];
    #pragma unroll
    for (int i = 0; i < 16; ++i) {
        const int v = offset + local[i];
        row_start[base + i] = v;
        cursor[base + i] = v;
    }
    if (tid == 255) row_start[4096] = NE;
}

__global__ __launch_bounds__(256) void csr_scatter(const int* __restrict__ eidx,
                                                   int* __restrict__ cursor,
                                                   int* __restrict__ eids)
{
    const int e = blockIdx.x * 256 + threadIdx.x;
    const int pos = atomicAdd(&cursor[eidx[NE + e]], 1);
    eids[pos] = e;
}

// ---------------------------------------------------------------------------
// Fused message + aggregation (gather, bf16 in/out):
// agg[n] = sum_{e: dst=n} relu(P[src_e] + eattr_e @ Wme + b_msg)
// ---------------------------------------------------------------------------
__global__ __launch_bounds__(256) void agg_kernel(
    const unsigned short* __restrict__ P, const int* __restrict__ eidx,
    const float* __restrict__ eattr, const float* __restrict__ Wme,
    const float* __restrict__ bmsg, const int* __restrict__ row_start,
    const int* __restrict__ eids, unsigned short* __restrict__ agg)
{
    const int n = blockIdx.x * 4 + (threadIdx.x >> 6);
    const int lane = threadIdx.x & 63;
    const int c = lane * 4;
    const float4 bm = *(const float4*)(bmsg + c);
    const float4 w0 = *(const float4*)(Wme + 0 * 256 + c);
    const float4 w1 = *(const float4*)(Wme + 1 * 256 + c);
    const float4 w2 = *(const float4*)(Wme + 2 * 256 + c);
    const float4 w3 = *(const float4*)(Wme + 3 * 256 + c);
    const float4 w4 = *(const float4*)(Wme + 4 * 256 + c);
    const int beg = row_start[n];
    const int end = row_start[n + 1];
    float ax = 0.f, ay = 0.f, az = 0.f, aw = 0.f;
    for (int idx = beg; idx < end; ++idx) {
        const int e = eids[idx];
        const int src = eidx[e];
        const float a0 = eattr[e * NET + 0];
        const float a1 = eattr[e * NET + 1];
        const float a2 = eattr[e * NET + 2];
        const float a3 = eattr[e * NET + 3];
        const float a4 = eattr[e * NET + 4];
        const uint2 pu = *(const uint2*)(P + (size_t)src * 256 + c);
        float vx = __builtin_bit_cast(float, pu.x << 16) + bm.x;
        float vy = __builtin_bit_cast(float, pu.x & 0xffff0000u) + bm.y;
        float vz = __builtin_bit_cast(float, pu.y << 16) + bm.z;
        float vw = __builtin_bit_cast(float, pu.y & 0xffff0000u) + bm.w;
        vx = fmaf(a0, w0.x, vx); vy = fmaf(a0, w0.y, vy); vz = fmaf(a0, w0.z, vz); vw = fmaf(a0, w0.w, vw);
        vx = fmaf(a1, w1.x, vx); vy = fmaf(a1, w1.y, vy); vz = fmaf(a1, w1.z, vz); vw = fmaf(a1, w1.w, vw);
        vx = fmaf(a2, w2.x, vx); vy = fmaf(a2, w2.y, vy); vz = fmaf(a2, w2.z, vz); vw = fmaf(a2, w2.w, vw);
        vx = fmaf(a3, w3.x, vx); vy = fmaf(a3, w3.y, vy); vz = fmaf(a3, w3.z, vz); vw = fmaf(a3, w3.w, vw);
        vx = fmaf(a4, w4.x, vx); vy = fmaf(a4, w4.y, vy); vz = fmaf(a4, w4.z, vz); vw = fmaf(a4, w4.w, vw);
        ax += fmaxf(vx, 0.f); ay += fmaxf(vy, 0.f);
        az += fmaxf(vz, 0.f); aw += fmaxf(vw, 0.f);
    }
    uint2 o;
    o.x = (unsigned)f2bf(ax) | ((unsigned)f2bf(ay) << 16);
    o.y = (unsigned)f2bf(az) | ((unsigned)f2bf(aw) << 16);
    *(uint2*)(agg + (size_t)n * 256 + c) = o;
}

// ---------------------------------------------------------------------------
__global__ void prop_kernel(const float* __restrict__ props, const float* __restrict__ W_prop,
                            const float* __restrict__ b_prop, const float* __restrict__ W_add,
                            const float* __restrict__ b_add, float* __restrict__ prop_add)
{
    const int b = blockIdx.x;
    const int c = threadIdx.x;
    const float pv = props[b];
    float acc = b_add[c];
    for (int p = 0; p < PD; ++p) {
        const float e = fmaf(pv, W_prop[p], b_prop[p]);
        acc = fmaf(e, W_add[(256 + p) * 256 + c], acc);
    }
    prop_add[b * 256 + c] = acc;
}

// ---------------------------------------------------------------------------
// Wf[c][t] = sum_j W3[c][j]*W_out[j][t] (blocks 0..255);  bf (block 256)
// ---------------------------------------------------------------------------
__global__ __launch_bounds__(256) void wf_kernel(
    const float* __restrict__ W3, const float* __restrict__ b3,
    const float* __restrict__ W_out, const float* __restrict__ b_out,
    float* __restrict__ Wf, float* __restrict__ bf)
{
    __shared__ float part[4][NET];
    const int tid = threadIdx.x;
    const int blk = blockIdx.x;
    float acc[NET] = {0.f, 0.f, 0.f, 0.f, 0.f};
    if (blk < 256) {
        #pragma unroll
        for (int rep = 0; rep < 2; ++rep) {
            const int j = rep * 256 + tid;
            const float wv = W3[(size_t)blk * 512 + j];
            #pragma unroll
            for (int t = 0; t < NET; ++t) acc[t] = fmaf(wv, W_out[j * NET + t], acc[t]);
        }
    } else {
        #pragma unroll
        for (int rep = 0; rep < 2; ++rep) {
            const int j = rep * 256 + tid;
            const float wv = b3[j];
            #pragma unroll
            for (int t = 0; t < NET; ++t) acc[t] = fmaf(wv, W_out[j * NET + t], acc[t]);
        }
    }
    #pragma unroll
    for (int t = 0; t < NET; ++t)
        for (int off = 32; off >= 1; off >>= 1) acc[t] += __shfl_down(acc[t], off);
    if ((tid & 63) == 0) {
        #pragma unroll
        for (int t = 0; t < NET; ++t) part[tid >> 6][t] = acc[t];
    }
    __syncthreads();
    if (tid == 0) {
        float s[NET];
        #pragma unroll
        for (int t = 0; t < NET; ++t)
            s[t] = part[0][t] + part[1][t] + part[2][t] + part[3][t];
        if (blk < 256) {
            #pragma unroll
            for (int t = 0; t < NET; ++t) Wf[blk * NET + t] = s[t];
        } else {
            #pragma unroll
            for (int t = 0; t < NET; ++t) bf[t] = s[t] + b_out[t];
        }
    }
}

// ---------------------------------------------------------------------------
// Fused per-node pipeline. Grid 256 blocks x 16-row tiles, 4 waves.
// mode 0: act = relu(x@W_in+b);            P = act@Wm.   writes hout, out1(P)
// mode 1: act = relu(h@Wua + agg@Wub + b); P = act@Wm.   writes hout, out1(P)
// mode 2: act = relu(h@Wua + agg@Wub + b); embg = act@W_add + prop_add;
//         out1 = embg@W1a; out2 = embg@W1b.
// ---------------------------------------------------------------------------
__global__ __launch_bounds__(256, 4) void fused_node(
    const float* __restrict__ x,
    const unsigned short* __restrict__ hin,
    const unsigned short* __restrict__ aggin,
    const unsigned short* __restrict__ WaT,
    const unsigned short* __restrict__ WbT,
    const float* __restrict__ bias1,
    const unsigned short* __restrict__ Wp2T,
    const float* __restrict__ prop_add,
    const unsigned short* __restrict__ W1aT_,
    const unsigned short* __restrict__ W1bT_,
    unsigned short* __restrict__ hout,
    unsigned short* __restrict__ out1,
    unsigned short* __restrict__ out2,
    int mode)
{
    __shared__ __align__(16) unsigned short As[16 * 40];
    __shared__ __align__(16) unsigned short Bs[256 * 40];
    __shared__ __align__(16) unsigned short Hs[16 * HSTR];
    __shared__ __align__(16) unsigned short H2s[16 * HSTR];

    const int tid = threadIdx.x;
    const int w = tid >> 6;
    const int lane = tid & 63;
    const int q = lane >> 4;
    const int tx = lane & 15;
    const int m0 = blockIdx.x * 16;

    f32x4 acc[4];
    #pragma unroll
    for (int cc = 0; cc < 4; ++cc) acc[cc] = (f32x4)0.f;

    // ---- phase 1: act[16,256] ----
    const int Ktot = (mode == 0) ? 192 : 512;
    const int Kstr = (mode == 0) ? 192 : 256;
    for (int k0 = 0; k0 < Ktot; k0 += 32) {
        {   // A tile: 16 rows x 32 k
            const int r = tid >> 4;
            const int kk = (tid & 15) * 2;
            if (mode == 0) {
                const float2 v = *(const float2*)(x + (size_t)(m0 + r) * 192 + k0 + kk);
                const unsigned int pk = (unsigned)f2bf(v.x) | ((unsigned)f2bf(v.y) << 16);
                *(unsigned int*)&As[r * 40 + kk] = pk;
            } else {
                const unsigned short* sel = (k0 < 256) ? hin : aggin;
                const int ks = k0 & 255;
                *(unsigned int*)&As[r * 40 + kk] =
                    *(const unsigned int*)(sel + (size_t)(m0 + r) * 256 + ks + kk);
            }
        }
        {   // B tile: 256 cols x 32 k
            const unsigned short* WT = (mode == 0) ? WaT : ((k0 < 256) ? WaT : WbT);
            const int ks = (mode == 0) ? k0 : (k0 & 255);
            const int4* sp = (const int4*)(WT + (size_t)tid * Kstr + ks);
            const int4 v0 = sp[0], v1 = sp[1], v2 = sp[2], v3 = sp[3];
            int4* dp = (int4*)&Bs[tid * 40];
            dp[0] = v0; dp[1] = v1; dp[2] = v2; dp[3] = v3;
        }
        __syncthreads();
        const short8 af = *(const short8*)&As[tx * 40 + q * 8];
        #pragma unroll
        for (int cc = 0; cc < 4; ++cc) {
            const short8 bfr = *(const short8*)&Bs[(w * 64 + cc * 16 + tx) * 40 + q * 8];
            acc[cc] = __builtin_amdgcn_mfma_f32_16x16x32_bf16(af, bfr, acc[cc], 0, 0, 0);
        }
        __syncthreads();
    }
    #pragma unroll
    for (int cc = 0; cc < 4; ++cc) {
        const int col = w * 64 + cc * 16 + tx;
        const float bv = bias1[col];
        #pragma unroll
        for (int r = 0; r < 4; ++r) {
            const int row = q * 4 + r;
            const unsigned short us = f2bf(fmaxf(acc[cc][r] + bv, 0.f));
            Hs[row * HSTR + col] = us;
            if (mode < 2) hout[(size_t)(m0 + row) * 256 + col] = us;
        }
        acc[cc] = (f32x4)0.f;
    }

    // ---- phase 2: P = act@Wp2 (modes 0,1) or embg = act@W_add + prop (mode 2) ----
    for (int k0 = 0; k0 < 256; k0 += 32) {
        const int4* sp = (const int4*)(Wp2T + (size_t)tid * 256 + k0);
        const int4 v0 = sp[0], v1 = sp[1], v2 = sp[2], v3 = sp[3];
        int4* dp = (int4*)&Bs[tid * 40];
        dp[0] = v0; dp[1] = v1; dp[2] = v2; dp[3] = v3;
        __syncthreads();
        const short8 af = ld_frag(&Hs[tx * HSTR + k0 + q * 8]);
        #pragma unroll
        for (int cc = 0; cc < 4; ++cc) {
            const short8 bfr = *(const short8*)&Bs[(w * 64 + cc * 16 + tx) * 40 + q * 8];
            acc[cc] = __builtin_amdgcn_mfma_f32_16x16x32_bf16(af, bfr, acc[cc], 0, 0, 0);
        }
        __syncthreads();
    }
    const int bidx = m0 >> 6;
    #pragma unroll
    for (int cc = 0; cc < 4; ++cc) {
        const int col = w * 64 + cc * 16 + tx;
        #pragma unroll
        for (int r = 0; r < 4; ++r) {
            const int row = q * 4 + r;
            if (mode < 2) {
                out1[(size_t)(m0 + row) * 256 + col] = f2bf(acc[cc][r]);
            } else {
                const float v = acc[cc][r] + prop_add[bidx * 256 + col];
                H2s[row * HSTR + col] = f2bf(v);
            }
        }
        acc[cc] = (f32x4)0.f;
    }

    // ---- phase 2b (mode 2): A1 = embg@W1a, A2 = embg@W1b ----
    if (mode == 2) {
        for (int which = 0; which < 2; ++which) {
            const unsigned short* WT = which ? W1bT_ : W1aT_;
            unsigned short* outp = which ? out2 : out1;
            for (int k0 = 0; k0 < 256; k0 += 32) {
                const int4* sp = (const int4*)(WT + (size_t)tid * 256 + k0);
                const int4 v0 = sp[0], v1 = sp[1], v2 = sp[2], v3 = sp[3];
                int4* dp = (int4*)&Bs[tid * 40];
                dp[0] = v0; dp[1] = v1; dp[2] = v2; dp[3] = v3;
                __syncthreads();
                const short8 af = ld_frag(&H2s[tx * HSTR + k0 + q * 8]);
                #pragma unroll
                for (int cc = 0; cc < 4; ++cc) {
                    const short8 bfr = *(const short8*)&Bs[(w * 64 + cc * 16 + tx) * 40 + q * 8];
                    acc[cc] = __builtin_amdgcn_mfma_f32_16x16x32_bf16(af, bfr, acc[cc], 0, 0, 0);
                }
                __syncthreads();
            }
            #pragma unroll
            for (int cc = 0; cc < 4; ++cc) {
                const int col = w * 64 + cc * 16 + tx;
                #pragma unroll
                for (int r = 0; r < 4; ++r) {
                    const int row = q * 4 + r;
                    outp[(size_t)(m0 + row) * 256 + col] = f2bf(acc[cc][r]);
                }
                acc[cc] = (f32x4)0.f;
            }
        }
    }
}

// ---------------------------------------------------------------------------
// Fused pair MLP + CE with MFMA: 64 pairs/block, bf16 A1/A2 gather,
// W2 staged in 128-col chunks (3 blocks/CU).
// ---------------------------------------------------------------------------
__global__ __launch_bounds__(256, 4) void pair_mfma(
    const unsigned short* __restrict__ A1t, const unsigned short* __restrict__ A2t,
    const float* __restrict__ b1, const unsigned short* __restrict__ W2T,
    const float* __restrict__ b2, const float* __restrict__ Wf,
    const float* __restrict__ bfp,
    const int* __restrict__ sel_b, const int* __restrict__ sel_i,
    const int* __restrict__ sel_j, const int* __restrict__ golden,
    float* __restrict__ out)
{
    __shared__ __align__(16) unsigned short H1s[64 * HSTR];
    __shared__ __align__(16) unsigned short Bs[128 * 40];
    __shared__ int sidx[64], didx[64], gold[64];
    __shared__ float red[16];

    const int tid = threadIdx.x;
    const int e0 = blockIdx.x * 64;
    if (tid < 64) {
        const int e = e0 + tid;
        const int b = sel_b[e];
        sidx[tid] = b * N_PER_B + sel_i[e];
        didx[tid] = b * N_PER_B + sel_j[e];
        gold[tid] = golden[e];
    }
    __syncthreads();

    const float b1c = b1[tid];
    for (int p = 0; p < 64; ++p) {
        const float v = b2f(A1t[(size_t)sidx[p] * 256 + tid])
                      + b2f(A2t[(size_t)didx[p] * 256 + tid]) + b1c;
        H1s[p * HSTR + tid] = f2bf(fmaxf(v, 0.f));
    }

    const int w = tid >> 6;
    const int lane = tid & 63;
    const int q = lane >> 4;
    const int tx = lane & 15;

    f32x4 acc[16];
    #pragma unroll
    for (int a = 0; a < 16; ++a) acc[a] = (f32x4)0.f;

    for (int k0 = 0; k0 < 256; k0 += 32) {
        #pragma unroll
        for (int nh = 0; nh < 2; ++nh) {
            {   // stage 128 cols x 32 k of W2T
                const int nl = tid >> 1;
                const int kq = (tid & 1) * 16;
                const int4* sp = (const int4*)(W2T + (size_t)(nh * 128 + nl) * 256 + k0 + kq);
                const int4 v0 = sp[0], v1 = sp[1];
                int4* dp = (int4*)&Bs[nl * 40 + kq];
                dp[0] = v0; dp[1] = v1;
            }
            __syncthreads();
            const short8 af = ld_frag(&H1s[(w * 16 + tx) * HSTR + k0 + q * 8]);
            #pragma unroll
            for (int c = 0; c < 8; ++c) {
                const short8 bfr = *(const short8*)&Bs[(c * 16 + tx) * 40 + q * 8];
                acc[nh * 8 + c] = __builtin_amdgcn_mfma_f32_16x16x32_bf16(af, bfr, acc[nh * 8 + c], 0, 0, 0);
            }
            __syncthreads();
        }
    }

    float pl[4][NET];
    #pragma unroll
    for (int r = 0; r < 4; ++r)
        #pragma unroll
        for (int t = 0; t < NET; ++t) pl[r][t] = 0.f;

    #pragma unroll
    for (int a = 0; a < 16; ++a) {
        const int col = ((a >> 3) << 7) + ((a & 7) << 4) + tx;
        const float b2v = b2[col];
        float wfv[NET];
        #pragma unroll
        for (int t = 0; t < NET; ++t) wfv[t] = Wf[col * NET + t];
        #pragma unroll
        for (int r = 0; r < 4; ++r) {
            const float v = fmaxf(acc[a][r] + b2v, 0.f);
            #pragma unroll
            for (int t = 0; t < NET; ++t) pl[r][t] = fmaf(v, wfv[t], pl[r][t]);
        }
    }
    #pragma unroll
    for (int r = 0; r < 4; ++r)
        #pragma unroll
        for (int t = 0; t < NET; ++t) {
            float v = pl[r][t];
            for (int off = 1; off < 16; off <<= 1) v += __shfl_xor(v, off, 16);
            pl[r][t] = v;
        }

    if (tx == 0) {
        float lsum = 0.f;
        #pragma unroll
        for (int r = 0; r < 4; ++r) {
            const int p = w * 16 + q * 4 + r;
            float lg[NET];
            #pragma unroll
            for (int t = 0; t < NET; ++t) lg[t] = pl[r][t] + bfp[t];
            float mx = lg[0];
            #pragma unroll
            for (int t = 1; t < NET; ++t) mx = fmaxf(mx, lg[t]);
            float s = 0.f;
            #pragma unroll
            for (int t = 0; t < NET; ++t) s += expf(lg[t] - mx);
            lsum += mx + logf(s) - lg[gold[p]];
        }
        red[w * 4 + q] = lsum;
    }
    __syncthreads();
    if (tid == 0) {
        float s = 0.f;
        #pragma unroll
        for (int i = 0; i < 16; ++i) s += red[i];
        atomicAdd(out, s * (1.0f / NSEL));
    }
}

// ---------------------------------------------------------------------------
extern "C" void kernel_launch(void* const* d_in, const int* in_sizes, int n_in,
                              void* d_out, int out_size, void* d_ws, size_t ws_size,
                              hipStream_t stream) {
    (void)in_sizes; (void)n_in; (void)out_size; (void)ws_size;
    const float* x      = (const float*)d_in[0];
    const int*   eidx   = (const int*)d_in[1];
    const float* eattr  = (const float*)d_in[2];
    const float* props  = (const float*)d_in[3];
    const int*   sel_b  = (const int*)d_in[4];
    const int*   sel_i  = (const int*)d_in[5];
    const int*   sel_j  = (const int*)d_in[6];
    const int*   golden = (const int*)d_in[7];
    const float* W_prop = (const float*)d_in[8];
    const float* b_prop = (const float*)d_in[9];
    const float* W_in   = (const float*)d_in[10];
    const float* b_in   = (const float*)d_in[11];
    const float* W_msg  = (const float*)d_in[12];
    const float* b_msg  = (const float*)d_in[13];
    const float* W_upd  = (const float*)d_in[14];
    const float* b_upd  = (const float*)d_in[15];
    const float* W_add  = (const float*)d_in[16];
    const float* b_add  = (const float*)d_in[17];
    const float* W1     = (const float*)d_in[18];
    const float* b1     = (const float*)d_in[19];
    const float* W2     = (const float*)d_in[20];
    const float* b2     = (const float*)d_in[21];
    const float* W3     = (const float*)d_in[22];
    const float* b3     = (const float*)d_in[23];
    const float* W_out  = (const float*)d_in[24];
    const float* b_out  = (const float*)d_in[25];

    const size_t SEG = (size_t)BN * 256;   // elements per activation buffer
    unsigned short* hA   = (unsigned short*)d_ws;
    unsigned short* hB   = hA + SEG;
    unsigned short* Pb   = hB + SEG;
    unsigned short* agb  = Pb + SEG;
    unsigned short* A1b  = agb + SEG;
    unsigned short* A2b  = A1b + SEG;
    unsigned short* wbf  = A2b + SEG;        // bf16 transposed weights
    unsigned short* W_inT  = wbf;            // [256][192]
    unsigned short* WmT    = wbf + 49152;    // [256][256]
    unsigned short* WuaT   = WmT + 65536;
    unsigned short* WubT   = WuaT + 65536;
    unsigned short* W_addT = WubT + 65536;
    unsigned short* W1aT   = W_addT + 65536;
    unsigned short* W1bT   = W1aT + 65536;
    unsigned short* W2T    = W1bT + 65536;
    float* prop_add = (float*)(W2T + 65536); // [64][256]
    float* Wf  = prop_add + 64 * 256;
    float* bfv = Wf + 256 * NET;
    int* deg       = (int*)(bfv + 16);
    int* row_start = deg + 4096;             // [4097]
    int* cursor    = row_start + 4112;
    int* eids      = cursor + 4096;          // [16384]

    conv_weights<<<dim3(16, 8), 256, 0, stream>>>(W_in, W_msg, W_upd, W_add, W1, W2, wbf);

    hipMemsetAsync(deg, 0, 4096 * sizeof(int), stream);
    csr_hist<<<NE / 256, 256, 0, stream>>>(eidx, deg);
    csr_scan<<<1, 256, 0, stream>>>(deg, row_start, cursor);
    csr_scatter<<<NE / 256, 256, 0, stream>>>(eidx, cursor, eids);
    prop_kernel<<<N_PER_B, 256, 0, stream>>>(props, W_prop, b_prop, W_add, b_add, prop_add);
    wf_kernel<<<257, 256, 0, stream>>>(W3, b3, W_out, b_out, Wf, bfv);

    // h0 = relu(x@W_in+b); P0 = h0@Wm
    fused_node<<<256, 256, 0, stream>>>(x, nullptr, nullptr, W_inT, nullptr, b_in,
                                        WmT, nullptr, nullptr, nullptr, hA, Pb, nullptr, 0);

    unsigned short* hc = hA;
    unsigned short* hn = hB;
    for (int t = 0; t < 3; ++t) {
        agg_kernel<<<BN / 4, 256, 0, stream>>>(Pb, eidx, eattr, W_msg + 256 * 256, b_msg,
                                               row_start, eids, agb);
        fused_node<<<256, 256, 0, stream>>>(nullptr, hc, agb, WuaT, WubT, b_upd,
                                            WmT, nullptr, nullptr, nullptr, hn, Pb, nullptr, 1);
        unsigned short* tmp = hc; hc = hn; hn = tmp;
    }
    agg_kernel<<<BN / 4, 256, 0, stream>>>(Pb, eidx, eattr, W_msg + 256 * 256, b_msg,
                                           row_start, eids, agb);
    // h4, embg, A1, A2
    fused_node<<<256, 256, 0, stream>>>(nullptr, hc, agb, WuaT, WubT, b_upd,
                                        W_addT, prop_add, W1aT, W1bT, nullptr, A1b, A2b, 2);

    hipMemsetAsync(d_out, 0, sizeof(float), stream);
    pair_mfma<<<NSEL / 64, 256, 0, stream>>>(A1b, A2b, b1, W2T, b2, Wf, bfv,
                                             sel_b, sel_i, sel_j, golden, (float*)d_out);
}

// Round 6
// 301.302 us; speedup vs baseline: 3.0448x; 1.2023x over previous
//
#include <hip/hip_runtime.h>
#include <math.h>

#define BN 4096
#define N_PER_B 64
#define NE 16384
#define NSEL 65536
#define NET 5
#define PD 64
#define H1STR 260   // LDS row stride (shorts): 130 dw == 2 mod 32 -> 2-way (free) for b64 frag reads

typedef float f32x4 __attribute__((ext_vector_type(4)));
typedef float f32x16 __attribute__((ext_vector_type(16)));
typedef short short8 __attribute__((ext_vector_type(8)));
typedef short short4v __attribute__((ext_vector_type(4)));

__device__ __forceinline__ unsigned short f2bf(float f) {
    unsigned int u = __builtin_bit_cast(unsigned int, f);
    u += 0x7fff + ((u >> 16) & 1);          // RNE
    return (unsigned short)(u >> 16);
}
__device__ __forceinline__ float bf_lo(unsigned int u) {
    return __builtin_bit_cast(float, u << 16);
}
__device__ __forceinline__ float bf_hi(unsigned int u) {
    return __builtin_bit_cast(float, u & 0xffff0000u);
}
__device__ __forceinline__ unsigned int pack2(float a, float b) {
    return (unsigned)f2bf(a) | ((unsigned)f2bf(b) << 16);
}
// 16B fragment from 8B-aligned LDS (row stride H1STR keeps banks 2-way)
__device__ __forceinline__ short8 ld_frag(const unsigned short* p) {
    const short4v lo = *(const short4v*)(p);
    const short4v hi = *(const short4v*)(p + 4);
    return __builtin_shufflevector(lo, hi, 0, 1, 2, 3, 4, 5, 6, 7);
}
// h1 element: relu(bf16+bf16+bf16) on packed pairs
__device__ __forceinline__ unsigned int addrelu2(unsigned int a, unsigned int b, unsigned int c) {
    const float lo = fmaxf(bf_lo(a) + bf_lo(b) + bf_lo(c), 0.f);
    const float hi = fmaxf(bf_hi(a) + bf_hi(b) + bf_hi(c), 0.f);
    return pack2(lo, hi);
}

// ---------------------------------------------------------------------------
// Preamble mega-kernel (independent jobs by blockIdx range):
//  [0,128)   conv_weights: fp32 [K][256] -> bf16 [256][K] transposed
//  [128,192) csr histogram
//  [192,256) prop_add
//  [256,513) Wfold = W3@W_out (bf16 WfT[16][256], zero-padded rows 5..15) + bfv
//  [513,641) ET[e][c] = eattr_e @ Wm_e + b_msg   (bf16, round-invariant)
// ---------------------------------------------------------------------------
__global__ __launch_bounds__(256) void k_pre(
    const float* __restrict__ W_in, const float* __restrict__ W_msg,
    const float* __restrict__ W_upd, const float* __restrict__ W_add,
    const float* __restrict__ W1, const float* __restrict__ W2,
    const float* __restrict__ W3, const float* __restrict__ b3,
    const float* __restrict__ W_out, const float* __restrict__ b_out,
    const float* __restrict__ props, const float* __restrict__ W_prop,
    const float* __restrict__ b_prop, const float* __restrict__ b_add,
    const float* __restrict__ b_msg, const float* __restrict__ eattr,
    const int* __restrict__ eidx,
    unsigned short* __restrict__ wbf, unsigned short* __restrict__ WfT,
    float* __restrict__ bfv, float* __restrict__ prop_add,
    int* __restrict__ deg, unsigned short* __restrict__ ET)
{
    __shared__ __align__(16) char smem[16640];
    const int blk = blockIdx.x;
    const int tid = threadIdx.x;

    if (blk < 128) {                          // ---- weight convert/transpose
        float (*s)[65] = (float(*)[65])smem;
        const int wsel = blk >> 4;
        const int sub = blk & 15;
        const float* src; unsigned short* dst; int K = 256;
        switch (wsel) {
            case 0: src = W_in;              dst = wbf;                         K = 192; break;
            case 1: src = W_msg;             dst = wbf + 49152;                 break;
            case 2: src = W_upd;             dst = wbf + 49152 + 65536;         break;
            case 3: src = W_upd + 256 * 256; dst = wbf + 49152 + 2 * 65536;     break;
            case 4: src = W_add;             dst = wbf + 49152 + 3 * 65536;     break;
            case 5: src = W1;                dst = wbf + 49152 + 4 * 65536;     break;
            case 6: src = W1 + 256 * 256;    dst = wbf + 49152 + 5 * 65536;     break;
            default: src = W2;               dst = wbf + 49152 + 6 * 65536;     break;
        }
        const int k0 = (sub >> 2) * 64;
        const int n0 = (sub & 3) * 64;
        if (k0 >= K) return;
        const int tn = tid & 63;
        const int tg = tid >> 6;
        #pragma unroll
        for (int i = 0; i < 16; ++i) {
            const int kk = tg * 16 + i;
            s[kk][tn] = src[(size_t)(k0 + kk) * 256 + n0 + tn];
        }
        __syncthreads();
        #pragma unroll
        for (int i = 0; i < 16; ++i) {
            const int nn = tg * 16 + i;
            dst[(size_t)(n0 + nn) * K + k0 + tn] = f2bf(s[tn][nn]);
        }
    } else if (blk < 192) {                   // ---- csr histogram
        const int e = (blk - 128) * 256 + tid;
        atomicAdd(&deg[eidx[NE + e]], 1);
    } else if (blk < 256) {                   // ---- prop_add
        const int b = blk - 192;
        const float pv = props[b];
        float acc = b_add[tid];
        for (int p = 0; p < PD; ++p) {
            const float e = fmaf(pv, W_prop[p], b_prop[p]);
            acc = fmaf(e, W_add[(256 + p) * 256 + tid], acc);
        }
        prop_add[b * 256 + tid] = acc;
    } else if (blk < 513) {                   // ---- Wfold + bfv
        float* part = (float*)smem;           // [4][NET]
        const int cb = blk - 256;             // 0..256
        float acc[NET] = {0.f, 0.f, 0.f, 0.f, 0.f};
        #pragma unroll
        for (int rep = 0; rep < 2; ++rep) {
            const int j = rep * 256 + tid;
            const float wv = (cb < 256) ? W3[(size_t)cb * 512 + j] : b3[j];
            #pragma unroll
            for (int t = 0; t < NET; ++t) acc[t] = fmaf(wv, W_out[j * NET + t], acc[t]);
        }
        #pragma unroll
        for (int t = 0; t < NET; ++t)
            for (int off = 32; off >= 1; off >>= 1) acc[t] += __shfl_down(acc[t], off);
        if ((tid & 63) == 0) {
            #pragma unroll
            for (int t = 0; t < NET; ++t) part[(tid >> 6) * NET + t] = acc[t];
        }
        __syncthreads();
        if (tid == 0) {
            float s[NET];
            #pragma unroll
            for (int t = 0; t < NET; ++t)
                s[t] = part[t] + part[NET + t] + part[2 * NET + t] + part[3 * NET + t];
            if (cb < 256) {
                #pragma unroll
                for (int t = 0; t < NET; ++t) WfT[t * 256 + cb] = f2bf(s[t]);
                #pragma unroll
                for (int t = NET; t < 16; ++t) WfT[t * 256 + cb] = 0;
            } else {
                #pragma unroll
                for (int t = 0; t < NET; ++t) bfv[t] = s[t] + b_out[t];
            }
        }
    } else {                                  // ---- edge term ET
        float* ea = (float*)smem;             // [128*5]
        const int eb = (blk - 513) * 128;
        if (tid < 160)
            *(float4*)&ea[tid * 4] = *(const float4*)(eattr + (size_t)eb * 5 + tid * 4);
        __syncthreads();
        const float* Wme = W_msg + 256 * 256;
        const float w0 = Wme[0 * 256 + tid];
        const float w1 = Wme[1 * 256 + tid];
        const float w2 = Wme[2 * 256 + tid];
        const float w3 = Wme[3 * 256 + tid];
        const float w4 = Wme[4 * 256 + tid];
        const float bm = b_msg[tid];
        for (int i = 0; i < 128; ++i) {
            const float* a = ea + i * 5;
            float v = bm;
            v = fmaf(a[0], w0, v); v = fmaf(a[1], w1, v); v = fmaf(a[2], w2, v);
            v = fmaf(a[3], w3, v); v = fmaf(a[4], w4, v);
            ET[(size_t)(eb + i) * 256 + tid] = f2bf(v);
        }
    }
}

// ---------------------------------------------------------------------------
__global__ __launch_bounds__(256) void csr_scan(const int* __restrict__ deg,
                                                int* __restrict__ row_start,
                                                int* __restrict__ cursor)
{
    __shared__ int sums[256];
    const int tid = threadIdx.x;
    const int base = tid * 16;
    int local[16];
    int s = 0;
    #pragma unroll
    for (int i = 0; i < 16; ++i) { local[i] = s; s += deg[base + i]; }
    sums[tid] = s;
    __syncthreads();
    for (int off = 1; off < 256; off <<= 1) {
        const int v = sums[tid];
        const int add = (tid >= off) ? sums[tid - off] : 0;
        __syncthreads();
        sums[tid] = v + add;
        __syncthreads();
    }
    const int offset = (tid == 0) ? 0 : sums[tid - 1];
    #pragma unroll
    for (int i = 0; i < 16; ++i) {
        const int v = offset + local[i];
        row_start[base + i] = v;
        cursor[base + i] = v;
    }
    if (tid == 255) row_start[4096] = NE;
}

__global__ __launch_bounds__(256) void csr_scatter(const int* __restrict__ eidx,
                                                   int* __restrict__ cursor,
                                                   int* __restrict__ eids)
{
    const int e = blockIdx.x * 256 + threadIdx.x;
    const int pos = atomicAdd(&cursor[eidx[NE + e]], 1);
    eids[pos] = e;
}

// ---------------------------------------------------------------------------
// agg[n] = sum_{e: dst=n} relu(P[src_e] + ET[e])   (all bf16)
// ---------------------------------------------------------------------------
__global__ __launch_bounds__(256) void agg2(
    const unsigned short* __restrict__ P, const unsigned short* __restrict__ ET,
    const int* __restrict__ eidx, const int* __restrict__ row_start,
    const int* __restrict__ eids, unsigned short* __restrict__ agg)
{
    const int n = blockIdx.x * 4 + (threadIdx.x >> 6);
    const int lane = threadIdx.x & 63;
    const int c = lane * 4;
    const int beg = row_start[n];
    const int end = row_start[n + 1];
    float a0 = 0.f, a1 = 0.f, a2 = 0.f, a3 = 0.f;
    for (int idx = beg; idx < end; ++idx) {
        const int e = eids[idx];
        const int src = eidx[e];
        const uint2 pu = *(const uint2*)(P + (size_t)src * 256 + c);
        const uint2 eu = *(const uint2*)(ET + (size_t)e * 256 + c);
        a0 += fmaxf(bf_lo(pu.x) + bf_lo(eu.x), 0.f);
        a1 += fmaxf(bf_hi(pu.x) + bf_hi(eu.x), 0.f);
        a2 += fmaxf(bf_lo(pu.y) + bf_lo(eu.y), 0.f);
        a3 += fmaxf(bf_hi(pu.y) + bf_hi(eu.y), 0.f);
    }
    uint2 o; o.x = pack2(a0, a1); o.y = pack2(a2, a3);
    *(uint2*)(agg + (size_t)n * 256 + c) = o;
}

// ---------------------------------------------------------------------------
// Fused per-node pipeline, direct-global MFMA fragments (no B staging).
// 16 rows/block (grid 256), 4 waves; wave w owns cols w*64..+63 (4 tiles).
// mode 0: act=relu(x@W_in+b);            P=act@Wm       -> hout, out1
// mode 1: act=relu(h@Wua+agg@Wub+b);     P=act@Wm       -> hout (distinct buf), out1
// mode 2: act=relu(h@Wua+agg@Wub+b); embg=act@W_add+prop; out1=embg@W1a; out2=embg@W1b
// All in/out buffers are distinct (double-buffered h) — no aliasing.
// ---------------------------------------------------------------------------
__global__ __launch_bounds__(256) void fnode(
    const float* __restrict__ x, const unsigned short* __restrict__ hbuf,
    const unsigned short* __restrict__ agb,
    const unsigned short* __restrict__ WaT, const unsigned short* __restrict__ WbT,
    const float* __restrict__ bias1,
    const unsigned short* __restrict__ Wp2T, const float* __restrict__ prop_add,
    const unsigned short* __restrict__ W1aT, const unsigned short* __restrict__ W1bT,
    unsigned short* __restrict__ hout, unsigned short* __restrict__ out1,
    unsigned short* __restrict__ out2, int mode)
{
    __shared__ __align__(16) unsigned short Hs[16 * 264];
    __shared__ __align__(16) unsigned short H2s[16 * 264];
    const int tid = threadIdx.x;
    const int w = tid >> 6;
    const int lane = tid & 63;
    const int q = lane >> 4;
    const int tx = lane & 15;
    const int m0 = blockIdx.x * 16;

    f32x4 acc[4];
    #pragma unroll
    for (int cc = 0; cc < 4; ++cc) acc[cc] = (f32x4)0.f;

    // ---- phase 1: act ----
    const int nch = (mode == 0) ? 6 : 16;
    const int Kstr = (mode == 0) ? 192 : 256;
    for (int s = 0; s < nch; ++s) {
        const int k0 = s * 32;
        short8 af;
        if (mode == 0) {
            const float* ap = x + (size_t)(m0 + tx) * 192 + k0 + q * 8;
            const float4 v0 = *(const float4*)ap;
            const float4 v1 = *(const float4*)(ap + 4);
            af[0] = (short)f2bf(v0.x); af[1] = (short)f2bf(v0.y);
            af[2] = (short)f2bf(v0.z); af[3] = (short)f2bf(v0.w);
            af[4] = (short)f2bf(v1.x); af[5] = (short)f2bf(v1.y);
            af[6] = (short)f2bf(v1.z); af[7] = (short)f2bf(v1.w);
        } else {
            const unsigned short* ap = (k0 < 256) ? hbuf : agb;
            af = *(const short8*)(ap + (size_t)(m0 + tx) * 256 + (k0 & 255) + q * 8);
        }
        const unsigned short* WT = (mode == 0) ? WaT : ((k0 < 256) ? WaT : WbT);
        const int kk = (mode == 0) ? k0 : (k0 & 255);
        #pragma unroll
        for (int cc = 0; cc < 4; ++cc) {
            const int col = w * 64 + cc * 16 + tx;
            const short8 bfr = *(const short8*)(WT + (size_t)col * Kstr + kk + q * 8);
            acc[cc] = __builtin_amdgcn_mfma_f32_16x16x32_bf16(af, bfr, acc[cc], 0, 0, 0);
        }
    }
    #pragma unroll
    for (int cc = 0; cc < 4; ++cc) {
        const int col = w * 64 + cc * 16 + tx;
        const float bv = bias1[col];
        #pragma unroll
        for (int r = 0; r < 4; ++r) {
            const int row = q * 4 + r;
            const unsigned short us = f2bf(fmaxf(acc[cc][r] + bv, 0.f));
            Hs[row * 264 + col] = us;
            if (mode < 2) hout[(size_t)(m0 + row) * 256 + col] = us;
        }
        acc[cc] = (f32x4)0.f;
    }
    __syncthreads();

    // ---- phase 2: act @ Wp2 ----
    for (int s = 0; s < 8; ++s) {
        const int k0 = s * 32;
        const short8 af = *(const short8*)&Hs[tx * 264 + k0 + q * 8];
        #pragma unroll
        for (int cc = 0; cc < 4; ++cc) {
            const int col = w * 64 + cc * 16 + tx;
            const short8 bfr = *(const short8*)(Wp2T + (size_t)col * 256 + k0 + q * 8);
            acc[cc] = __builtin_amdgcn_mfma_f32_16x16x32_bf16(af, bfr, acc[cc], 0, 0, 0);
        }
    }
    if (mode < 2) {
        #pragma unroll
        for (int cc = 0; cc < 4; ++cc) {
            const int col = w * 64 + cc * 16 + tx;
            #pragma unroll
            for (int r = 0; r < 4; ++r)
                out1[(size_t)(m0 + q * 4 + r) * 256 + col] = f2bf(acc[cc][r]);
        }
        return;
    }
    const int bidx = m0 >> 6;
    #pragma unroll
    for (int cc = 0; cc < 4; ++cc) {
        const int col = w * 64 + cc * 16 + tx;
        const float pv = prop_add[bidx * 256 + col];
        #pragma unroll
        for (int r = 0; r < 4; ++r)
            H2s[(q * 4 + r) * 264 + col] = f2bf(acc[cc][r] + pv);
        acc[cc] = (f32x4)0.f;
    }
    __syncthreads();

    // ---- phase 2b: A1 = embg@W1a, A2 = embg@W1b ----
    for (int which = 0; which < 2; ++which) {
        const unsigned short* WT = which ? W1bT : W1aT;
        unsigned short* op = which ? out2 : out1;
        for (int s = 0; s < 8; ++s) {
            const int k0 = s * 32;
            const short8 af = *(const short8*)&H2s[tx * 264 + k0 + q * 8];
            #pragma unroll
            for (int cc = 0; cc < 4; ++cc) {
                const int col = w * 64 + cc * 16 + tx;
                const short8 bfr = *(const short8*)(WT + (size_t)col * 256 + k0 + q * 8);
                acc[cc] = __builtin_amdgcn_mfma_f32_16x16x32_bf16(af, bfr, acc[cc], 0, 0, 0);
            }
        }
        #pragma unroll
        for (int cc = 0; cc < 4; ++cc) {
            const int col = w * 64 + cc * 16 + tx;
            #pragma unroll
            for (int r = 0; r < 4; ++r)
                op[(size_t)(m0 + q * 4 + r) * 256 + col] = f2bf(acc[cc][r]);
            acc[cc] = (f32x4)0.f;
        }
    }
}

// ---------------------------------------------------------------------------
// Fused pair MLP + CE. 64 pairs/block (grid 1024).
// Gather (vectorized) -> H1 LDS -> 32x32x16 MFMA vs W2T direct-from-global ->
// relu+b2 -> H2 (overlays H1) -> 16x16x32 MFMA vs WfT -> CE.
// ---------------------------------------------------------------------------
__global__ __launch_bounds__(256) void pair_k(
    const unsigned short* __restrict__ A1t, const unsigned short* __restrict__ A2t,
    const float* __restrict__ b1, const unsigned short* __restrict__ W2T,
    const float* __restrict__ b2, const unsigned short* __restrict__ WfT,
    const float* __restrict__ bfv,
    const int* __restrict__ sel_b, const int* __restrict__ sel_i,
    const int* __restrict__ sel_j, const int* __restrict__ golden,
    float* __restrict__ out)
{
    __shared__ __align__(16) unsigned short sbuf[64 * H1STR];  // H1 then H2
    __shared__ __align__(16) unsigned short b1s[256];
    __shared__ float Lg[64 * 8];
    __shared__ int sidx[64], didx[64], gold[64];

    const int tid = threadIdx.x;
    const int w = tid >> 6;
    const int lane = tid & 63;
    const int q = lane >> 4;
    const int tx = lane & 15;
    const int m = lane & 31;
    const int hh = lane >> 5;
    const int e0 = blockIdx.x * 64;

    if (tid < 64) {
        const int e = e0 + tid;
        const int b = sel_b[e];
        sidx[tid] = b * N_PER_B + sel_i[e];
        didx[tid] = b * N_PER_B + sel_j[e];
        gold[tid] = golden[e];
    }
    b1s[tid] = f2bf(b1[tid]);
    __syncthreads();

    // ---- gather h1 = relu(A1[s]+A2[d]+b1): thread = (pair tid>>2, 64-col chunk tid&3)
    // 8 iterations x uint4 (8 shorts) covers the full 64-short chunk.
    {
        const int p = tid >> 2;
        const int chn = tid & 3;
        const unsigned short* r1 = A1t + (size_t)sidx[p] * 256 + chn * 64;
        const unsigned short* r2 = A2t + (size_t)didx[p] * 256 + chn * 64;
        unsigned short* dbase = sbuf + p * H1STR + chn * 64;
        #pragma unroll
        for (int g = 0; g < 8; ++g) {
            const uint4 u1 = *(const uint4*)(r1 + g * 8);
            const uint4 u2 = *(const uint4*)(r2 + g * 8);
            const uint4 ub = *(const uint4*)(b1s + chn * 64 + g * 8);
            uint2 lo2, hi2;
            lo2.x = addrelu2(u1.x, u2.x, ub.x);
            lo2.y = addrelu2(u1.y, u2.y, ub.y);
            hi2.x = addrelu2(u1.z, u2.z, ub.z);
            hi2.y = addrelu2(u1.w, u2.w, ub.w);
            *(uint2*)(dbase + g * 8) = lo2;        // 8B LDS writes (rows 8B-aligned)
            *(uint2*)(dbase + g * 8 + 4) = hi2;
        }
    }
    __syncthreads();

    // ---- main GEMM: wave w -> pair-tile pt=w&1 (32 pairs), col-half ch=w>>1 (128 cols)
    const int pt = w & 1;
    const int ch = w >> 1;
    f32x16 acc[4];
    #pragma unroll
    for (int cc = 0; cc < 4; ++cc) acc[cc] = (f32x16)0.f;

    const unsigned short* arow = sbuf + (size_t)(pt * 32 + m) * H1STR + hh * 8;
    const unsigned short* bb0 = W2T + (size_t)(ch * 128 + m) * 256 + hh * 8;
    #pragma unroll 4
    for (int s = 0; s < 16; ++s) {
        const short8 af = ld_frag(arow + s * 16);
        #pragma unroll
        for (int cc = 0; cc < 4; ++cc) {
            const short8 bfr = *(const short8*)(bb0 + (size_t)cc * 32 * 256 + s * 16);
            acc[cc] = __builtin_amdgcn_mfma_f32_32x32x16_bf16(af, bfr, acc[cc], 0, 0, 0);
        }
    }
    __syncthreads();   // all H1 reads complete before overwrite

    // ---- epilogue: h2 = relu(acc + b2) -> sbuf (as H2)
    #pragma unroll
    for (int cc = 0; cc < 4; ++cc) {
        const int col = ch * 128 + cc * 32 + m;
        const float bv = b2[col];
        #pragma unroll
        for (int reg = 0; reg < 16; ++reg) {
            const int prow = pt * 32 + (reg & 3) + 8 * (reg >> 2) + 4 * hh;
            sbuf[prow * H1STR + col] = f2bf(fmaxf(acc[cc][reg] + bv, 0.f));
        }
    }
    __syncthreads();

    // ---- logits = h2 @ Wfold (16x16x32, N padded to 16): wave w -> rows w*16..+15
    f32x4 accL = (f32x4)0.f;
    const unsigned short* a2row = sbuf + (size_t)(w * 16 + tx) * H1STR + q * 8;
    const unsigned short* bWf = WfT + (size_t)tx * 256 + q * 8;
    #pragma unroll
    for (int s = 0; s < 8; ++s) {
        const short8 af = ld_frag(a2row + s * 32);
        const short8 bfr = *(const short8*)(bWf + s * 32);
        accL = __builtin_amdgcn_mfma_f32_16x16x32_bf16(af, bfr, accL, 0, 0, 0);
    }
    if (tx < NET) {
        const float bb = bfv[tx];
        #pragma unroll
        for (int reg = 0; reg < 4; ++reg)
            Lg[(w * 16 + q * 4 + reg) * 8 + tx] = accL[reg] + bb;
    }
    __syncthreads();

    // ---- CE over 64 pairs (wave 0)
    if (tid < 64) {
        float lg[NET];
        #pragma unroll
        for (int t = 0; t < NET; ++t) lg[t] = Lg[tid * 8 + t];
        float mx = lg[0];
        #pragma unroll
        for (int t = 1; t < NET; ++t) mx = fmaxf(mx, lg[t]);
        float s = 0.f;
        #pragma unroll
        for (int t = 0; t < NET; ++t) s += expf(lg[t] - mx);
        float ls = mx + logf(s) - lg[gold[tid]];
        #pragma unroll
        for (int off = 32; off >= 1; off >>= 1) ls += __shfl_xor(ls, off);
        if (tid == 0) atomicAdd(out, ls * (1.0f / NSEL));
    }
}

// ---------------------------------------------------------------------------
extern "C" void kernel_launch(void* const* d_in, const int* in_sizes, int n_in,
                              void* d_out, int out_size, void* d_ws, size_t ws_size,
                              hipStream_t stream) {
    (void)in_sizes; (void)n_in; (void)out_size; (void)ws_size;
    const float* x      = (const float*)d_in[0];
    const int*   eidx   = (const int*)d_in[1];
    const float* eattr  = (const float*)d_in[2];
    const float* props  = (const float*)d_in[3];
    const int*   sel_b  = (const int*)d_in[4];
    const int*   sel_i  = (const int*)d_in[5];
    const int*   sel_j  = (const int*)d_in[6];
    const int*   golden = (const int*)d_in[7];
    const float* W_prop = (const float*)d_in[8];
    const float* b_prop = (const float*)d_in[9];
    const float* W_in   = (const float*)d_in[10];
    const float* b_in   = (const float*)d_in[11];
    const float* W_msg  = (const float*)d_in[12];
    const float* b_msg  = (const float*)d_in[13];
    const float* W_upd  = (const float*)d_in[14];
    const float* b_upd  = (const float*)d_in[15];
    const float* W_add  = (const float*)d_in[16];
    const float* b_add  = (const float*)d_in[17];
    const float* W1     = (const float*)d_in[18];
    const float* b1     = (const float*)d_in[19];
    const float* W2     = (const float*)d_in[20];
    const float* b2     = (const float*)d_in[21];
    const float* W3     = (const float*)d_in[22];
    const float* b3     = (const float*)d_in[23];
    const float* W_out  = (const float*)d_in[24];
    const float* b_out  = (const float*)d_in[25];

    const size_t SEG = (size_t)BN * 256;
    unsigned short* hA   = (unsigned short*)d_ws;   // h (double-buffered)
    unsigned short* hB   = hA + SEG;                // h alt; final A2
    unsigned short* Pb   = hB + SEG;                // P; final A1
    unsigned short* agb  = Pb + SEG;                // agg
    unsigned short* ET   = agb + SEG;               // [NE][256]
    unsigned short* wbf  = ET + (size_t)NE * 256;
    unsigned short* W_inT  = wbf;                   // [256][192]
    unsigned short* WmT    = wbf + 49152;
    unsigned short* WuaT   = WmT + 65536;
    unsigned short* WubT   = WuaT + 65536;
    unsigned short* W_addT = WubT + 65536;
    unsigned short* W1aT   = W_addT + 65536;
    unsigned short* W1bT   = W1aT + 65536;
    unsigned short* W2T    = W1bT + 65536;
    unsigned short* WfT    = W2T + 65536;           // [16][256]
    float* prop_add = (float*)(WfT + 4096);         // [64][256]
    float* bfv = prop_add + 64 * 256;               // [16]
    int* deg       = (int*)(bfv + 16);
    int* row_start = deg + 4096;                    // [4097]
    int* cursor    = row_start + 4104;
    int* eids      = cursor + 4096;                 // [NE]

    hipMemsetAsync(deg, 0, 4096 * sizeof(int), stream);
    k_pre<<<641, 256, 0, stream>>>(W_in, W_msg, W_upd, W_add, W1, W2, W3, b3,
                                   W_out, b_out, props, W_prop, b_prop, b_add,
                                   b_msg, eattr, eidx, wbf, WfT, bfv, prop_add,
                                   deg, ET);
    csr_scan<<<1, 256, 0, stream>>>(deg, row_start, cursor);
    csr_scatter<<<NE / 256, 256, 0, stream>>>(eidx, cursor, eids);

    // h0 = relu(x@W_in+b) -> hA; P = h0@Wm -> Pb
    fnode<<<256, 256, 0, stream>>>(x, nullptr, nullptr, W_inT, nullptr, b_in,
                                   WmT, nullptr, nullptr, nullptr,
                                   hA, Pb, nullptr, 0);
    unsigned short* hc = hA;
    unsigned short* hn = hB;
    for (int t = 0; t < 3; ++t) {
        agg2<<<BN / 4, 256, 0, stream>>>(Pb, ET, eidx, row_start, eids, agb);
        fnode<<<256, 256, 0, stream>>>(nullptr, hc, agb, WuaT, WubT, b_upd,
                                       WmT, nullptr, nullptr, nullptr,
                                       hn, Pb, nullptr, 1);
        unsigned short* tmp = hc; hc = hn; hn = tmp;
    }
    agg2<<<BN / 4, 256, 0, stream>>>(Pb, ET, eidx, row_start, eids, agb);
    // h4 -> embg -> A1 (Pb), A2 (hn = spare h buffer)
    fnode<<<256, 256, 0, stream>>>(nullptr, hc, agb, WuaT, WubT, b_upd,
                                   W_addT, prop_add, W1aT, W1bT,
                                   nullptr, Pb, hn, 2);

    hipMemsetAsync(d_out, 0, sizeof(float), stream);
    pair_k<<<NSEL / 64, 256, 0, stream>>>(Pb, hn, b1, W2T, b2, WfT, bfv,
                                          sel_b, sel_i, sel_j, golden, (float*)d_out);
}

// Round 7
// 275.225 us; speedup vs baseline: 3.3333x; 1.0947x over previous
//
#include <hip/hip_runtime.h>
#include <math.h>

#define BN 4096
#define N_PER_B 64
#define NE 16384
#define NSEL 65536
#define NET 5
#define PD 64
#define H1STR 260   // pair LDS stride (shorts): 130 dw == 2 mod 32 -> 2-way (free)
#define FSTR 264    // fstep LDS stride (shorts): 132 dw == 4 mod 32 -> 2-way for 16-lane reads

typedef float f32x4 __attribute__((ext_vector_type(4)));
typedef float f32x16 __attribute__((ext_vector_type(16)));
typedef short short8 __attribute__((ext_vector_type(8)));
typedef short short4v __attribute__((ext_vector_type(4)));

__device__ __forceinline__ unsigned short f2bf(float f) {
    unsigned int u = __builtin_bit_cast(unsigned int, f);
    u += 0x7fff + ((u >> 16) & 1);          // RNE
    return (unsigned short)(u >> 16);
}
__device__ __forceinline__ float bf_lo(unsigned int u) {
    return __builtin_bit_cast(float, u << 16);
}
__device__ __forceinline__ float bf_hi(unsigned int u) {
    return __builtin_bit_cast(float, u & 0xffff0000u);
}
__device__ __forceinline__ unsigned int pack2(float a, float b) {
    return (unsigned)f2bf(a) | ((unsigned)f2bf(b) << 16);
}
// 16B fragment from 8B-aligned LDS
__device__ __forceinline__ short8 ld_frag(const unsigned short* p) {
    const short4v lo = *(const short4v*)(p);
    const short4v hi = *(const short4v*)(p + 4);
    return __builtin_shufflevector(lo, hi, 0, 1, 2, 3, 4, 5, 6, 7);
}
__device__ __forceinline__ unsigned int addrelu2(unsigned int a, unsigned int b, unsigned int c) {
    const float lo = fmaxf(bf_lo(a) + bf_lo(b) + bf_lo(c), 0.f);
    const float hi = fmaxf(bf_hi(a) + bf_hi(b) + bf_hi(c), 0.f);
    return pack2(lo, hi);
}

// ---------------------------------------------------------------------------
// CSR build
// ---------------------------------------------------------------------------
__global__ __launch_bounds__(256) void k_hist(const int* __restrict__ eidx,
                                              int* __restrict__ deg)
{
    const int e = blockIdx.x * 256 + threadIdx.x;
    atomicAdd(&deg[eidx[NE + e]], 1);
}

__global__ __launch_bounds__(256) void csr_scan(const int* __restrict__ deg,
                                                int* __restrict__ row_start,
                                                int* __restrict__ cursor)
{
    __shared__ int sums[256];
    const int tid = threadIdx.x;
    const int base = tid * 16;
    int local[16];
    int s = 0;
    #pragma unroll
    for (int i = 0; i < 16; ++i) { local[i] = s; s += deg[base + i]; }
    sums[tid] = s;
    __syncthreads();
    for (int off = 1; off < 256; off <<= 1) {
        const int v = sums[tid];
        const int add = (tid >= off) ? sums[tid - off] : 0;
        __syncthreads();
        sums[tid] = v + add;
        __syncthreads();
    }
    const int offset = (tid == 0) ? 0 : sums[tid - 1];
    #pragma unroll
    for (int i = 0; i < 16; ++i) {
        const int v = offset + local[i];
        row_start[base + i] = v;
        cursor[base + i] = v;
    }
    if (tid == 255) row_start[4096] = NE;
}

// stores src node per CSR slot and the slot of each edge (for ET placement)
__global__ __launch_bounds__(256) void csr_scatter(const int* __restrict__ eidx,
                                                   int* __restrict__ cursor,
                                                   int* __restrict__ srcs,
                                                   int* __restrict__ epos)
{
    const int e = blockIdx.x * 256 + threadIdx.x;
    const int pos = atomicAdd(&cursor[eidx[NE + e]], 1);
    srcs[pos] = eidx[e];
    epos[e] = pos;
}

// ---------------------------------------------------------------------------
// Preamble mega-kernel:
//  [0,128)    weight convert/transpose fp32 [K][256] -> bf16 [256][K]
//  [128,192)  prop_add
//  [192,449)  Wfold = W3@W_out -> bf16 WfT[16][256] (rows 5..15 zero) + bfv
//  [449,577)  ETc[pos][c] = eattr_e @ Wm_e + b_msg  (CSR-ordered via epos)
// ---------------------------------------------------------------------------
__global__ __launch_bounds__(256) void k_pre(
    const float* __restrict__ W_in, const float* __restrict__ W_msg,
    const float* __restrict__ W_upd, const float* __restrict__ W_add,
    const float* __restrict__ W1, const float* __restrict__ W2,
    const float* __restrict__ W3, const float* __restrict__ b3,
    const float* __restrict__ W_out, const float* __restrict__ b_out,
    const float* __restrict__ props, const float* __restrict__ W_prop,
    const float* __restrict__ b_prop, const float* __restrict__ b_add,
    const float* __restrict__ b_msg, const float* __restrict__ eattr,
    const int* __restrict__ epos,
    unsigned short* __restrict__ wbf, unsigned short* __restrict__ WfT,
    float* __restrict__ bfv, float* __restrict__ prop_add,
    unsigned short* __restrict__ ETc)
{
    __shared__ __align__(16) char smem[16704];
    const int blk = blockIdx.x;
    const int tid = threadIdx.x;

    if (blk < 128) {                          // ---- weight convert/transpose
        float (*s)[65] = (float(*)[65])smem;
        const int wsel = blk >> 4;
        const int sub = blk & 15;
        const float* src; unsigned short* dst; int K = 256;
        switch (wsel) {
            case 0: src = W_in;              dst = wbf;                         K = 192; break;
            case 1: src = W_msg;             dst = wbf + 49152;                 break;
            case 2: src = W_upd;             dst = wbf + 49152 + 65536;         break;
            case 3: src = W_upd + 256 * 256; dst = wbf + 49152 + 2 * 65536;     break;
            case 4: src = W_add;             dst = wbf + 49152 + 3 * 65536;     break;
            case 5: src = W1;                dst = wbf + 49152 + 4 * 65536;     break;
            case 6: src = W1 + 256 * 256;    dst = wbf + 49152 + 5 * 65536;     break;
            default: src = W2;               dst = wbf + 49152 + 6 * 65536;     break;
        }
        const int k0 = (sub >> 2) * 64;
        const int n0 = (sub & 3) * 64;
        if (k0 >= K) return;
        const int tn = tid & 63;
        const int tg = tid >> 6;
        #pragma unroll
        for (int i = 0; i < 16; ++i) {
            const int kk = tg * 16 + i;
            s[kk][tn] = src[(size_t)(k0 + kk) * 256 + n0 + tn];
        }
        __syncthreads();
        #pragma unroll
        for (int i = 0; i < 16; ++i) {
            const int nn = tg * 16 + i;
            dst[(size_t)(n0 + nn) * K + k0 + tn] = f2bf(s[tn][nn]);
        }
    } else if (blk < 192) {                   // ---- prop_add
        const int b = blk - 128;
        const float pv = props[b];
        float acc = b_add[tid];
        for (int p = 0; p < PD; ++p) {
            const float e = fmaf(pv, W_prop[p], b_prop[p]);
            acc = fmaf(e, W_add[(256 + p) * 256 + tid], acc);
        }
        prop_add[b * 256 + tid] = acc;
    } else if (blk < 449) {                   // ---- Wfold + bfv
        float* part = (float*)smem;           // [4][NET]
        const int cb = blk - 192;             // 0..256
        float acc[NET] = {0.f, 0.f, 0.f, 0.f, 0.f};
        #pragma unroll
        for (int rep = 0; rep < 2; ++rep) {
            const int j = rep * 256 + tid;
            const float wv = (cb < 256) ? W3[(size_t)cb * 512 + j] : b3[j];
            #pragma unroll
            for (int t = 0; t < NET; ++t) acc[t] = fmaf(wv, W_out[j * NET + t], acc[t]);
        }
        #pragma unroll
        for (int t = 0; t < NET; ++t)
            for (int off = 32; off >= 1; off >>= 1) acc[t] += __shfl_down(acc[t], off);
        if ((tid & 63) == 0) {
            #pragma unroll
            for (int t = 0; t < NET; ++t) part[(tid >> 6) * NET + t] = acc[t];
        }
        __syncthreads();
        if (tid == 0) {
            float s[NET];
            #pragma unroll
            for (int t = 0; t < NET; ++t)
                s[t] = part[t] + part[NET + t] + part[2 * NET + t] + part[3 * NET + t];
            if (cb < 256) {
                #pragma unroll
                for (int t = 0; t < NET; ++t) WfT[t * 256 + cb] = f2bf(s[t]);
                #pragma unroll
                for (int t = NET; t < 16; ++t) WfT[t * 256 + cb] = 0;
            } else {
                #pragma unroll
                for (int t = 0; t < NET; ++t) bfv[t] = s[t] + b_out[t];
            }
        }
    } else {                                  // ---- edge term ET (CSR-ordered)
        float* ea = (float*)smem;             // [128*5]
        int* eposs = (int*)(smem + 2560 + 64);
        const int eb = (blk - 449) * 128;
        if (tid < 160)
            *(float4*)&ea[tid * 4] = *(const float4*)(eattr + (size_t)eb * 5 + tid * 4);
        if (tid < 128) eposs[tid] = epos[eb + tid];
        __syncthreads();
        const float* Wme = W_msg + 256 * 256;
        const float w0 = Wme[0 * 256 + tid];
        const float w1 = Wme[1 * 256 + tid];
        const float w2 = Wme[2 * 256 + tid];
        const float w3 = Wme[3 * 256 + tid];
        const float w4 = Wme[4 * 256 + tid];
        const float bm = b_msg[tid];
        for (int i = 0; i < 128; ++i) {
            const float* a = ea + i * 5;
            float v = bm;
            v = fmaf(a[0], w0, v); v = fmaf(a[1], w1, v); v = fmaf(a[2], w2, v);
            v = fmaf(a[3], w3, v); v = fmaf(a[4], w4, v);
            ETc[(size_t)eposs[i] * 256 + tid] = f2bf(v);
        }
    }
}

// ---------------------------------------------------------------------------
// Fused node step: agg (CSR gather) + act GEMM + second GEMM(s).
// 1024 threads = 16 waves; 16 node-rows/block (grid 256); wave w -> 16 cols.
// mode 0: act=relu(x@W_in+b);              P=act@Wm          -> hout, out1
// mode 1: agg; act=relu(h@Wua+agg@Wub+b);  P=act@Wm          -> hout, out1
// mode 2: agg; act=...; embg=act@W_add+prop; out1=embg@W1a; out2=embg@W1b
// ---------------------------------------------------------------------------
__global__ __launch_bounds__(1024) void fstep(
    const float* __restrict__ x, const unsigned short* __restrict__ hbuf,
    const unsigned short* __restrict__ Pin, const unsigned short* __restrict__ ETc,
    const int* __restrict__ row_start, const int* __restrict__ srcs,
    const unsigned short* __restrict__ WaT, const unsigned short* __restrict__ WbT,
    const float* __restrict__ bias1,
    const unsigned short* __restrict__ Wp2T, const float* __restrict__ prop_add,
    const unsigned short* __restrict__ W1aT, const unsigned short* __restrict__ W1bT,
    unsigned short* __restrict__ hout, unsigned short* __restrict__ out1,
    unsigned short* __restrict__ out2, int mode)
{
    __shared__ __align__(16) unsigned short Hg[16 * FSTR];   // staged h tile
    __shared__ __align__(16) unsigned short Ag[16 * FSTR];   // agg tile
    __shared__ __align__(16) unsigned short Hs[16 * FSTR];   // act
    __shared__ __align__(16) unsigned short H2s[16 * FSTR];  // embg (mode 2)
    const int tid = threadIdx.x;
    const int w = tid >> 6;          // 0..15
    const int lane = tid & 63;
    const int q = lane >> 4;
    const int tx = lane & 15;
    const int m0 = blockIdx.x * 16;
    const int col = w * 16 + tx;

    // ---- phase A: stage h tile + agg tile (modes 1,2)
    if (mode != 0) {
        {
            const int r = tid >> 6;
            const int c4 = (tid & 63) * 4;
            *(uint2*)&Hg[r * FSTR + c4] =
                *(const uint2*)(hbuf + (size_t)(m0 + r) * 256 + c4);
        }
        {
            const int node = m0 + w;          // wave w <-> node row w
            const int beg = row_start[node];
            const int end = row_start[node + 1];
            const int c = lane * 4;
            float a0 = 0.f, a1 = 0.f, a2 = 0.f, a3 = 0.f;
            for (int idx = beg; idx < end; ++idx) {
                const int src = srcs[idx];
                const uint2 pu = *(const uint2*)(Pin + (size_t)src * 256 + c);
                const uint2 eu = *(const uint2*)(ETc + (size_t)idx * 256 + c);
                a0 += fmaxf(bf_lo(pu.x) + bf_lo(eu.x), 0.f);
                a1 += fmaxf(bf_hi(pu.x) + bf_hi(eu.x), 0.f);
                a2 += fmaxf(bf_lo(pu.y) + bf_lo(eu.y), 0.f);
                a3 += fmaxf(bf_hi(pu.y) + bf_hi(eu.y), 0.f);
            }
            uint2 o; o.x = pack2(a0, a1); o.y = pack2(a2, a3);
            *(uint2*)&Ag[w * FSTR + c] = o;
        }
        __syncthreads();
    }

    // ---- phase B: act = relu(A@W + b), wave w -> one 16-col tile
    f32x4 acc = (f32x4)0.f;
    if (mode == 0) {
        #pragma unroll
        for (int s = 0; s < 6; ++s) {
            const int k0 = s * 32;
            const float* ap = x + (size_t)(m0 + tx) * 192 + k0 + q * 8;
            const float4 v0 = *(const float4*)ap;
            const float4 v1 = *(const float4*)(ap + 4);
            short8 af;
            af[0] = (short)f2bf(v0.x); af[1] = (short)f2bf(v0.y);
            af[2] = (short)f2bf(v0.z); af[3] = (short)f2bf(v0.w);
            af[4] = (short)f2bf(v1.x); af[5] = (short)f2bf(v1.y);
            af[6] = (short)f2bf(v1.z); af[7] = (short)f2bf(v1.w);
            const short8 bfr = *(const short8*)(WaT + (size_t)col * 192 + k0 + q * 8);
            acc = __builtin_amdgcn_mfma_f32_16x16x32_bf16(af, bfr, acc, 0, 0, 0);
        }
    } else {
        #pragma unroll
        for (int s = 0; s < 8; ++s) {
            const int k0 = s * 32;
            const short8 af = *(const short8*)&Hg[tx * FSTR + k0 + q * 8];
            const short8 bfr = *(const short8*)(WaT + (size_t)col * 256 + k0 + q * 8);
            acc = __builtin_amdgcn_mfma_f32_16x16x32_bf16(af, bfr, acc, 0, 0, 0);
        }
        #pragma unroll
        for (int s = 0; s < 8; ++s) {
            const int k0 = s * 32;
            const short8 af = *(const short8*)&Ag[tx * FSTR + k0 + q * 8];
            const short8 bfr = *(const short8*)(WbT + (size_t)col * 256 + k0 + q * 8);
            acc = __builtin_amdgcn_mfma_f32_16x16x32_bf16(af, bfr, acc, 0, 0, 0);
        }
    }
    {
        const float bv = bias1[col];
        #pragma unroll
        for (int r = 0; r < 4; ++r) {
            const int row = q * 4 + r;
            const unsigned short us = f2bf(fmaxf(acc[r] + bv, 0.f));
            Hs[row * FSTR + col] = us;
            if (mode < 2) hout[(size_t)(m0 + row) * 256 + col] = us;
        }
    }
    __syncthreads();

    // ---- phase C: act @ Wp2
    acc = (f32x4)0.f;
    #pragma unroll
    for (int s = 0; s < 8; ++s) {
        const int k0 = s * 32;
        const short8 af = *(const short8*)&Hs[tx * FSTR + k0 + q * 8];
        const short8 bfr = *(const short8*)(Wp2T + (size_t)col * 256 + k0 + q * 8);
        acc = __builtin_amdgcn_mfma_f32_16x16x32_bf16(af, bfr, acc, 0, 0, 0);
    }
    if (mode < 2) {
        #pragma unroll
        for (int r = 0; r < 4; ++r)
            out1[(size_t)(m0 + q * 4 + r) * 256 + col] = f2bf(acc[r]);
        return;
    }
    {
        const float pv = prop_add[(m0 >> 6) * 256 + col];
        #pragma unroll
        for (int r = 0; r < 4; ++r)
            H2s[(q * 4 + r) * FSTR + col] = f2bf(acc[r] + pv);
    }
    __syncthreads();

    // ---- phase 2b: A1 = embg@W1a, A2 = embg@W1b
    for (int which = 0; which < 2; ++which) {
        const unsigned short* WT = which ? W1bT : W1aT;
        unsigned short* op = which ? out2 : out1;
        acc = (f32x4)0.f;
        #pragma unroll
        for (int s = 0; s < 8; ++s) {
            const int k0 = s * 32;
            const short8 af = *(const short8*)&H2s[tx * FSTR + k0 + q * 8];
            const short8 bfr = *(const short8*)(WT + (size_t)col * 256 + k0 + q * 8);
            acc = __builtin_amdgcn_mfma_f32_16x16x32_bf16(af, bfr, acc, 0, 0, 0);
        }
        #pragma unroll
        for (int r = 0; r < 4; ++r)
            op[(size_t)(m0 + q * 4 + r) * 256 + col] = f2bf(acc[r]);
    }
}

// ---------------------------------------------------------------------------
// Fused pair MLP + CE. 64 pairs/block, 512 threads = 8 waves (grid 1024... 512).
// wave w: pairs (w&1)*32.., cols (w>>1)*64.. (2x 32x32x16 tiles).
// ---------------------------------------------------------------------------
__global__ __launch_bounds__(512) void pair_k(
    const unsigned short* __restrict__ A1t, const unsigned short* __restrict__ A2t,
    const float* __restrict__ b1, const unsigned short* __restrict__ W2T,
    const float* __restrict__ b2, const unsigned short* __restrict__ WfT,
    const float* __restrict__ bfv,
    const int* __restrict__ sel_b, const int* __restrict__ sel_i,
    const int* __restrict__ sel_j, const int* __restrict__ golden,
    float* __restrict__ out)
{
    __shared__ __align__(16) unsigned short sbuf[64 * H1STR];  // H1 then H2
    __shared__ __align__(16) unsigned short b1s[256];
    __shared__ float Lg[64 * 8];
    __shared__ int sidx[64], didx[64], gold[64];

    const int tid = threadIdx.x;
    const int w = tid >> 6;          // 0..7
    const int lane = tid & 63;
    const int q = lane >> 4;
    const int tx = lane & 15;
    const int m = lane & 31;
    const int hh = lane >> 5;
    const int e0 = blockIdx.x * 64;

    if (tid < 64) {
        const int e = e0 + tid;
        const int b = sel_b[e];
        sidx[tid] = b * N_PER_B + sel_i[e];
        didx[tid] = b * N_PER_B + sel_j[e];
        gold[tid] = golden[e];
    }
    if (tid < 256) b1s[tid] = f2bf(b1[tid]);
    __syncthreads();

    // ---- gather h1 = relu(A1[s]+A2[d]+b1): thread = (pair tid>>3, 32-col chunk tid&7)
    {
        const int p = tid >> 3;
        const int chn = tid & 7;
        const unsigned short* r1 = A1t + (size_t)sidx[p] * 256 + chn * 32;
        const unsigned short* r2 = A2t + (size_t)didx[p] * 256 + chn * 32;
        unsigned short* dbase = sbuf + p * H1STR + chn * 32;
        #pragma unroll
        for (int g = 0; g < 4; ++g) {
            const uint4 u1 = *(const uint4*)(r1 + g * 8);
            const uint4 u2 = *(const uint4*)(r2 + g * 8);
            const uint4 ub = *(const uint4*)(b1s + chn * 32 + g * 8);
            uint2 lo2, hi2;
            lo2.x = addrelu2(u1.x, u2.x, ub.x);
            lo2.y = addrelu2(u1.y, u2.y, ub.y);
            hi2.x = addrelu2(u1.z, u2.z, ub.z);
            hi2.y = addrelu2(u1.w, u2.w, ub.w);
            *(uint2*)(dbase + g * 8) = lo2;
            *(uint2*)(dbase + g * 8 + 4) = hi2;
        }
    }
    __syncthreads();

    // ---- main GEMM: wave w -> pt=w&1 (32 pairs), cg=w>>1 (64 cols, 2 tiles)
    const int pt = w & 1;
    const int cg = w >> 1;
    f32x16 acc[2];
    acc[0] = (f32x16)0.f; acc[1] = (f32x16)0.f;

    const unsigned short* arow = sbuf + (size_t)(pt * 32 + m) * H1STR + hh * 8;
    const unsigned short* bb0 = W2T + (size_t)(cg * 64 + m) * 256 + hh * 8;
    #pragma unroll 4
    for (int s = 0; s < 16; ++s) {
        const short8 af = ld_frag(arow + s * 16);
        #pragma unroll
        for (int cc = 0; cc < 2; ++cc) {
            const short8 bfr = *(const short8*)(bb0 + (size_t)cc * 32 * 256 + s * 16);
            acc[cc] = __builtin_amdgcn_mfma_f32_32x32x16_bf16(af, bfr, acc[cc], 0, 0, 0);
        }
    }
    __syncthreads();   // all H1 reads complete before overwrite

    // ---- epilogue: h2 = relu(acc + b2) -> sbuf (as H2)
    #pragma unroll
    for (int cc = 0; cc < 2; ++cc) {
        const int col = cg * 64 + cc * 32 + m;
        const float bv = b2[col];
        #pragma unroll
        for (int reg = 0; reg < 16; ++reg) {
            const int prow = pt * 32 + (reg & 3) + 8 * (reg >> 2) + 4 * hh;
            sbuf[prow * H1STR + col] = f2bf(fmaxf(acc[cc][reg] + bv, 0.f));
        }
    }
    __syncthreads();

    // ---- logits = h2 @ Wfold (waves 0..3, 16 rows each)
    if (w < 4) {
        f32x4 accL = (f32x4)0.f;
        const unsigned short* a2row = sbuf + (size_t)(w * 16 + tx) * H1STR + q * 8;
        const unsigned short* bWf = WfT + (size_t)tx * 256 + q * 8;
        #pragma unroll
        for (int s = 0; s < 8; ++s) {
            const short8 af = ld_frag(a2row + s * 32);
            const short8 bfr = *(const short8*)(bWf + s * 32);
            accL = __builtin_amdgcn_mfma_f32_16x16x32_bf16(af, bfr, accL, 0, 0, 0);
        }
        if (tx < NET) {
            const float bb = bfv[tx];
            #pragma unroll
            for (int reg = 0; reg < 4; ++reg)
                Lg[(w * 16 + q * 4 + reg) * 8 + tx] = accL[reg] + bb;
        }
    }
    __syncthreads();

    // ---- CE over 64 pairs (wave 0)
    if (tid < 64) {
        float lg[NET];
        #pragma unroll
        for (int t = 0; t < NET; ++t) lg[t] = Lg[tid * 8 + t];
        float mx = lg[0];
        #pragma unroll
        for (int t = 1; t < NET; ++t) mx = fmaxf(mx, lg[t]);
        float s = 0.f;
        #pragma unroll
        for (int t = 0; t < NET; ++t) s += expf(lg[t] - mx);
        float ls = mx + logf(s) - lg[gold[tid]];
        #pragma unroll
        for (int off = 32; off >= 1; off >>= 1) ls += __shfl_xor(ls, off);
        if (tid == 0) atomicAdd(out, ls * (1.0f / NSEL));
    }
}

// ---------------------------------------------------------------------------
extern "C" void kernel_launch(void* const* d_in, const int* in_sizes, int n_in,
                              void* d_out, int out_size, void* d_ws, size_t ws_size,
                              hipStream_t stream) {
    (void)in_sizes; (void)n_in; (void)out_size; (void)ws_size;
    const float* x      = (const float*)d_in[0];
    const int*   eidx   = (const int*)d_in[1];
    const float* eattr  = (const float*)d_in[2];
    const float* props  = (const float*)d_in[3];
    const int*   sel_b  = (const int*)d_in[4];
    const int*   sel_i  = (const int*)d_in[5];
    const int*   sel_j  = (const int*)d_in[6];
    const int*   golden = (const int*)d_in[7];
    const float* W_prop = (const float*)d_in[8];
    const float* b_prop = (const float*)d_in[9];
    const float* W_in   = (const float*)d_in[10];
    const float* b_in   = (const float*)d_in[11];
    const float* W_msg  = (const float*)d_in[12];
    const float* b_msg  = (const float*)d_in[13];
    const float* W_upd  = (const float*)d_in[14];
    const float* b_upd  = (const float*)d_in[15];
    const float* W_add  = (const float*)d_in[16];
    const float* b_add  = (const float*)d_in[17];
    const float* W1     = (const float*)d_in[18];
    const float* b1     = (const float*)d_in[19];
    const float* W2     = (const float*)d_in[20];
    const float* b2     = (const float*)d_in[21];
    const float* W3     = (const float*)d_in[22];
    const float* b3     = (const float*)d_in[23];
    const float* W_out  = (const float*)d_in[24];
    const float* b_out  = (const float*)d_in[25];

    const size_t SEG = (size_t)BN * 256;
    unsigned short* P0   = (unsigned short*)d_ws;   // P even rounds; final A1
    unsigned short* P1   = P0 + SEG;                // P odd rounds
    unsigned short* hA   = P1 + SEG;                // h double-buffer; final A2
    unsigned short* hB   = hA + SEG;
    unsigned short* ETc  = hB + SEG;                // [NE][256] CSR-ordered
    unsigned short* wbf  = ETc + (size_t)NE * 256;
    unsigned short* W_inT  = wbf;                   // [256][192]
    unsigned short* WmT    = wbf + 49152;
    unsigned short* WuaT   = WmT + 65536;
    unsigned short* WubT   = WuaT + 65536;
    unsigned short* W_addT = WubT + 65536;
    unsigned short* W1aT   = W_addT + 65536;
    unsigned short* W1bT   = W1aT + 65536;
    unsigned short* W2T    = W1bT + 65536;
    unsigned short* WfT    = W2T + 65536;           // [16][256]
    float* prop_add = (float*)(WfT + 4096);         // [64][256]
    float* bfv = prop_add + 64 * 256;               // [16]
    int* deg       = (int*)(bfv + 16);
    int* row_start = deg + 4096;                    // [4097]
    int* cursor    = row_start + 4104;
    int* srcs      = cursor + 4096;                 // [NE]
    int* epos      = srcs + NE;                     // [NE]

    hipMemsetAsync(deg, 0, 4096 * sizeof(int), stream);
    k_hist<<<NE / 256, 256, 0, stream>>>(eidx, deg);
    csr_scan<<<1, 256, 0, stream>>>(deg, row_start, cursor);
    csr_scatter<<<NE / 256, 256, 0, stream>>>(eidx, cursor, srcs, epos);
    k_pre<<<577, 256, 0, stream>>>(W_in, W_msg, W_upd, W_add, W1, W2, W3, b3,
                                   W_out, b_out, props, W_prop, b_prop, b_add,
                                   b_msg, eattr, epos, wbf, WfT, bfv, prop_add, ETc);

    // round 0: h0 = relu(x@W_in+b) -> hA; P0 = h0@Wm
    fstep<<<256, 1024, 0, stream>>>(x, nullptr, nullptr, ETc, row_start, srcs,
                                    W_inT, nullptr, b_in, WmT, nullptr, nullptr, nullptr,
                                    hA, P0, nullptr, 0);
    // rounds 1..3: agg(P) -> h' -> P'
    fstep<<<256, 1024, 0, stream>>>(nullptr, hA, P0, ETc, row_start, srcs,
                                    WuaT, WubT, b_upd, WmT, nullptr, nullptr, nullptr,
                                    hB, P1, nullptr, 1);
    fstep<<<256, 1024, 0, stream>>>(nullptr, hB, P1, ETc, row_start, srcs,
                                    WuaT, WubT, b_upd, WmT, nullptr, nullptr, nullptr,
                                    hA, P0, nullptr, 1);
    fstep<<<256, 1024, 0, stream>>>(nullptr, hA, P0, ETc, row_start, srcs,
                                    WuaT, WubT, b_upd, WmT, nullptr, nullptr, nullptr,
                                    hB, P1, nullptr, 1);
    // final: agg(P1) -> h4 -> embg -> A1 (P0), A2 (hA)
    fstep<<<256, 1024, 0, stream>>>(nullptr, hB, P1, ETc, row_start, srcs,
                                    WuaT, WubT, b_upd, W_addT, prop_add, W1aT, W1bT,
                                    nullptr, P0, hA, 2);

    hipMemsetAsync(d_out, 0, sizeof(float), stream);
    pair_k<<<NSEL / 64, 512, 0, stream>>>(P0, hA, b1, W2T, b2, WfT, bfv,
                                          sel_b, sel_i, sel_j, golden, (float*)d_out);
}

// Round 8
// 252.061 us; speedup vs baseline: 3.6396x; 1.0919x over previous
//
#include <hip/hip_runtime.h>
#include <math.h>

#define BN 4096
#define N_PER_B 64
#define NE 16384
#define NSEL 65536
#define NET 5
#define PD 64
#define H1STR 260   // pair LDS stride (shorts): 130 dw == 2 mod 32 -> 2-way (free)
#define FSTR 264    // fstep LDS stride
#define PTILES 4    // pair tiles per block

typedef float f32x4 __attribute__((ext_vector_type(4)));
typedef float f32x16 __attribute__((ext_vector_type(16)));
typedef short short8 __attribute__((ext_vector_type(8)));
typedef short short4v __attribute__((ext_vector_type(4)));

__device__ __forceinline__ unsigned short f2bf(float f) {
    unsigned int u = __builtin_bit_cast(unsigned int, f);
    u += 0x7fff + ((u >> 16) & 1);          // RNE
    return (unsigned short)(u >> 16);
}
__device__ __forceinline__ float bf_lo(unsigned int u) {
    return __builtin_bit_cast(float, u << 16);
}
__device__ __forceinline__ float bf_hi(unsigned int u) {
    return __builtin_bit_cast(float, u & 0xffff0000u);
}
__device__ __forceinline__ unsigned int pack2(float a, float b) {
    return (unsigned)f2bf(a) | ((unsigned)f2bf(b) << 16);
}
// 16B fragment from 8B-aligned LDS
__device__ __forceinline__ short8 ld_frag(const unsigned short* p) {
    const short4v lo = *(const short4v*)(p);
    const short4v hi = *(const short4v*)(p + 4);
    return __builtin_shufflevector(lo, hi, 0, 1, 2, 3, 4, 5, 6, 7);
}
__device__ __forceinline__ unsigned int addrelu2(unsigned int a, unsigned int b, unsigned int c) {
    const float lo = fmaxf(bf_lo(a) + bf_lo(b) + bf_lo(c), 0.f);
    const float hi = fmaxf(bf_hi(a) + bf_hi(b) + bf_hi(c), 0.f);
    return pack2(lo, hi);
}

// ---------------------------------------------------------------------------
// CSR build
// ---------------------------------------------------------------------------
__global__ __launch_bounds__(256) void k_hist(const int* __restrict__ eidx,
                                              int* __restrict__ deg)
{
    const int e = blockIdx.x * 256 + threadIdx.x;
    atomicAdd(&deg[eidx[NE + e]], 1);
}

__global__ __launch_bounds__(256) void csr_scan(const int* __restrict__ deg,
                                                int* __restrict__ row_start,
                                                int* __restrict__ cursor)
{
    __shared__ int sums[256];
    const int tid = threadIdx.x;
    const int base = tid * 16;
    int local[16];
    int s = 0;
    #pragma unroll
    for (int i = 0; i < 16; ++i) { local[i] = s; s += deg[base + i]; }
    sums[tid] = s;
    __syncthreads();
    for (int off = 1; off < 256; off <<= 1) {
        const int v = sums[tid];
        const int add = (tid >= off) ? sums[tid - off] : 0;
        __syncthreads();
        sums[tid] = v + add;
        __syncthreads();
    }
    const int offset = (tid == 0) ? 0 : sums[tid - 1];
    #pragma unroll
    for (int i = 0; i < 16; ++i) {
        const int v = offset + local[i];
        row_start[base + i] = v;
        cursor[base + i] = v;
    }
    if (tid == 255) row_start[4096] = NE;
}

__global__ __launch_bounds__(256) void csr_scatter(const int* __restrict__ eidx,
                                                   int* __restrict__ cursor,
                                                   int* __restrict__ srcs,
                                                   int* __restrict__ epos)
{
    const int e = blockIdx.x * 256 + threadIdx.x;
    const int pos = atomicAdd(&cursor[eidx[NE + e]], 1);
    srcs[pos] = eidx[e];
    epos[e] = pos;
}

// ---------------------------------------------------------------------------
// Preamble mega-kernel:
//  [0,128)    weight convert/transpose fp32 [K][256] -> bf16 [256][K]
//  [128,192)  prop_add
//  [192,449)  Wfold = W3@W_out -> bf16 WfT[16][256] (rows 5..15 zero) + bfv
//  [449,577)  ETc[pos][c] = eattr_e @ Wm_e + b_msg  (CSR-ordered via epos)
// ---------------------------------------------------------------------------
__global__ __launch_bounds__(256) void k_pre(
    const float* __restrict__ W_in, const float* __restrict__ W_msg,
    const float* __restrict__ W_upd, const float* __restrict__ W_add,
    const float* __restrict__ W1, const float* __restrict__ W2,
    const float* __restrict__ W3, const float* __restrict__ b3,
    const float* __restrict__ W_out, const float* __restrict__ b_out,
    const float* __restrict__ props, const float* __restrict__ W_prop,
    const float* __restrict__ b_prop, const float* __restrict__ b_add,
    const float* __restrict__ b_msg, const float* __restrict__ eattr,
    const int* __restrict__ epos,
    unsigned short* __restrict__ wbf, unsigned short* __restrict__ WfT,
    float* __restrict__ bfv, float* __restrict__ prop_add,
    unsigned short* __restrict__ ETc)
{
    __shared__ __align__(16) char smem[16704];
    const int blk = blockIdx.x;
    const int tid = threadIdx.x;

    if (blk < 128) {                          // ---- weight convert/transpose
        float (*s)[65] = (float(*)[65])smem;
        const int wsel = blk >> 4;
        const int sub = blk & 15;
        const float* src; unsigned short* dst; int K = 256;
        switch (wsel) {
            case 0: src = W_in;              dst = wbf;                         K = 192; break;
            case 1: src = W_msg;             dst = wbf + 49152;                 break;
            case 2: src = W_upd;             dst = wbf + 49152 + 65536;         break;
            case 3: src = W_upd + 256 * 256; dst = wbf + 49152 + 2 * 65536;     break;
            case 4: src = W_add;             dst = wbf + 49152 + 3 * 65536;     break;
            case 5: src = W1;                dst = wbf + 49152 + 4 * 65536;     break;
            case 6: src = W1 + 256 * 256;    dst = wbf + 49152 + 5 * 65536;     break;
            default: src = W2;               dst = wbf + 49152 + 6 * 65536;     break;
        }
        const int k0 = (sub >> 2) * 64;
        const int n0 = (sub & 3) * 64;
        if (k0 >= K) return;
        const int tn = tid & 63;
        const int tg = tid >> 6;
        #pragma unroll
        for (int i = 0; i < 16; ++i) {
            const int kk = tg * 16 + i;
            s[kk][tn] = src[(size_t)(k0 + kk) * 256 + n0 + tn];
        }
        __syncthreads();
        #pragma unroll
        for (int i = 0; i < 16; ++i) {
            const int nn = tg * 16 + i;
            dst[(size_t)(n0 + nn) * K + k0 + tn] = f2bf(s[tn][nn]);
        }
    } else if (blk < 192) {                   // ---- prop_add
        const int b = blk - 128;
        const float pv = props[b];
        float acc = b_add[tid];
        for (int p = 0; p < PD; ++p) {
            const float e = fmaf(pv, W_prop[p], b_prop[p]);
            acc = fmaf(e, W_add[(256 + p) * 256 + tid], acc);
        }
        prop_add[b * 256 + tid] = acc;
    } else if (blk < 449) {                   // ---- Wfold + bfv
        float* part = (float*)smem;           // [4][NET]
        const int cb = blk - 192;             // 0..256
        float acc[NET] = {0.f, 0.f, 0.f, 0.f, 0.f};
        #pragma unroll
        for (int rep = 0; rep < 2; ++rep) {
            const int j = rep * 256 + tid;
            const float wv = (cb < 256) ? W3[(size_t)cb * 512 + j] : b3[j];
            #pragma unroll
            for (int t = 0; t < NET; ++t) acc[t] = fmaf(wv, W_out[j * NET + t], acc[t]);
        }
        #pragma unroll
        for (int t = 0; t < NET; ++t)
            for (int off = 32; off >= 1; off >>= 1) acc[t] += __shfl_down(acc[t], off);
        if ((tid & 63) == 0) {
            #pragma unroll
            for (int t = 0; t < NET; ++t) part[(tid >> 6) * NET + t] = acc[t];
        }
        __syncthreads();
        if (tid == 0) {
            float s[NET];
            #pragma unroll
            for (int t = 0; t < NET; ++t)
                s[t] = part[t] + part[NET + t] + part[2 * NET + t] + part[3 * NET + t];
            if (cb < 256) {
                #pragma unroll
                for (int t = 0; t < NET; ++t) WfT[t * 256 + cb] = f2bf(s[t]);
                #pragma unroll
                for (int t = NET; t < 16; ++t) WfT[t * 256 + cb] = 0;
            } else {
                #pragma unroll
                for (int t = 0; t < NET; ++t) bfv[t] = s[t] + b_out[t];
            }
        }
    } else {                                  // ---- edge term ET (CSR-ordered)
        float* ea = (float*)smem;             // [128*5]
        int* eposs = (int*)(smem + 2560 + 64);
        const int eb = (blk - 449) * 128;
        if (tid < 160)
            *(float4*)&ea[tid * 4] = *(const float4*)(eattr + (size_t)eb * 5 + tid * 4);
        if (tid < 128) eposs[tid] = epos[eb + tid];
        __syncthreads();
        const float* Wme = W_msg + 256 * 256;
        const float w0 = Wme[0 * 256 + tid];
        const float w1 = Wme[1 * 256 + tid];
        const float w2 = Wme[2 * 256 + tid];
        const float w3 = Wme[3 * 256 + tid];
        const float w4 = Wme[4 * 256 + tid];
        const float bm = b_msg[tid];
        for (int i = 0; i < 128; ++i) {
            const float* a = ea + i * 5;
            float v = bm;
            v = fmaf(a[0], w0, v); v = fmaf(a[1], w1, v); v = fmaf(a[2], w2, v);
            v = fmaf(a[3], w3, v); v = fmaf(a[4], w4, v);
            ETc[(size_t)eposs[i] * 256 + tid] = f2bf(v);
        }
    }
}

// ---------------------------------------------------------------------------
// Fused node step: agg (CSR gather) + act GEMM + second GEMM(s).
// 1024 threads = 16 waves; 16 node-rows/block (grid 256); wave w -> 16 cols.
// ---------------------------------------------------------------------------
__global__ __launch_bounds__(1024) void fstep(
    const float* __restrict__ x, const unsigned short* __restrict__ hbuf,
    const unsigned short* __restrict__ Pin, const unsigned short* __restrict__ ETc,
    const int* __restrict__ row_start, const int* __restrict__ srcs,
    const unsigned short* __restrict__ WaT, const unsigned short* __restrict__ WbT,
    const float* __restrict__ bias1,
    const unsigned short* __restrict__ Wp2T, const float* __restrict__ prop_add,
    const unsigned short* __restrict__ W1aT, const unsigned short* __restrict__ W1bT,
    unsigned short* __restrict__ hout, unsigned short* __restrict__ out1,
    unsigned short* __restrict__ out2, int mode)
{
    __shared__ __align__(16) unsigned short Hg[16 * FSTR];   // staged h tile
    __shared__ __align__(16) unsigned short Ag[16 * FSTR];   // agg tile
    __shared__ __align__(16) unsigned short Hs[16 * FSTR];   // act
    __shared__ __align__(16) unsigned short H2s[16 * FSTR];  // embg (mode 2)
    const int tid = threadIdx.x;
    const int w = tid >> 6;          // 0..15
    const int lane = tid & 63;
    const int q = lane >> 4;
    const int tx = lane & 15;
    const int m0 = blockIdx.x * 16;
    const int col = w * 16 + tx;

    // ---- phase A: stage h tile + agg tile (modes 1,2)
    if (mode != 0) {
        {
            const int r = tid >> 6;
            const int c4 = (tid & 63) * 4;
            *(uint2*)&Hg[r * FSTR + c4] =
                *(const uint2*)(hbuf + (size_t)(m0 + r) * 256 + c4);
        }
        {
            const int node = m0 + w;          // wave w <-> node row w
            const int beg = row_start[node];
            const int end = row_start[node + 1];
            const int c = lane * 4;
            float a0 = 0.f, a1 = 0.f, a2 = 0.f, a3 = 0.f;
            for (int idx = beg; idx < end; ++idx) {
                const int src = srcs[idx];
                const uint2 pu = *(const uint2*)(Pin + (size_t)src * 256 + c);
                const uint2 eu = *(const uint2*)(ETc + (size_t)idx * 256 + c);
                a0 += fmaxf(bf_lo(pu.x) + bf_lo(eu.x), 0.f);
                a1 += fmaxf(bf_hi(pu.x) + bf_hi(eu.x), 0.f);
                a2 += fmaxf(bf_lo(pu.y) + bf_lo(eu.y), 0.f);
                a3 += fmaxf(bf_hi(pu.y) + bf_hi(eu.y), 0.f);
            }
            uint2 o; o.x = pack2(a0, a1); o.y = pack2(a2, a3);
            *(uint2*)&Ag[w * FSTR + c] = o;
        }
        __syncthreads();
    }

    // ---- phase B: act = relu(A@W + b), wave w -> one 16-col tile
    f32x4 acc = (f32x4)0.f;
    if (mode == 0) {
        #pragma unroll
        for (int s = 0; s < 6; ++s) {
            const int k0 = s * 32;
            const float* ap = x + (size_t)(m0 + tx) * 192 + k0 + q * 8;
            const float4 v0 = *(const float4*)ap;
            const float4 v1 = *(const float4*)(ap + 4);
            short8 af;
            af[0] = (short)f2bf(v0.x); af[1] = (short)f2bf(v0.y);
            af[2] = (short)f2bf(v0.z); af[3] = (short)f2bf(v0.w);
            af[4] = (short)f2bf(v1.x); af[5] = (short)f2bf(v1.y);
            af[6] = (short)f2bf(v1.z); af[7] = (short)f2bf(v1.w);
            const short8 bfr = *(const short8*)(WaT + (size_t)col * 192 + k0 + q * 8);
            acc = __builtin_amdgcn_mfma_f32_16x16x32_bf16(af, bfr, acc, 0, 0, 0);
        }
    } else {
        #pragma unroll
        for (int s = 0; s < 8; ++s) {
            const int k0 = s * 32;
            const short8 af = *(const short8*)&Hg[tx * FSTR + k0 + q * 8];
            const short8 bfr = *(const short8*)(WaT + (size_t)col * 256 + k0 + q * 8);
            acc = __builtin_amdgcn_mfma_f32_16x16x32_bf16(af, bfr, acc, 0, 0, 0);
        }
        #pragma unroll
        for (int s = 0; s < 8; ++s) {
            const int k0 = s * 32;
            const short8 af = *(const short8*)&Ag[tx * FSTR + k0 + q * 8];
            const short8 bfr = *(const short8*)(WbT + (size_t)col * 256 + k0 + q * 8);
            acc = __builtin_amdgcn_mfma_f32_16x16x32_bf16(af, bfr, acc, 0, 0, 0);
        }
    }
    {
        const float bv = bias1[col];
        #pragma unroll
        for (int r = 0; r < 4; ++r) {
            const int row = q * 4 + r;
            const unsigned short us = f2bf(fmaxf(acc[r] + bv, 0.f));
            Hs[row * FSTR + col] = us;
            if (mode < 2) hout[(size_t)(m0 + row) * 256 + col] = us;
        }
    }
    __syncthreads();

    // ---- phase C: act @ Wp2
    acc = (f32x4)0.f;
    #pragma unroll
    for (int s = 0; s < 8; ++s) {
        const int k0 = s * 32;
        const short8 af = *(const short8*)&Hs[tx * FSTR + k0 + q * 8];
        const short8 bfr = *(const short8*)(Wp2T + (size_t)col * 256 + k0 + q * 8);
        acc = __builtin_amdgcn_mfma_f32_16x16x32_bf16(af, bfr, acc, 0, 0, 0);
    }
    if (mode < 2) {
        #pragma unroll
        for (int r = 0; r < 4; ++r)
            out1[(size_t)(m0 + q * 4 + r) * 256 + col] = f2bf(acc[r]);
        return;
    }
    {
        const float pv = prop_add[(m0 >> 6) * 256 + col];
        #pragma unroll
        for (int r = 0; r < 4; ++r)
            H2s[(q * 4 + r) * FSTR + col] = f2bf(acc[r] + pv);
    }
    __syncthreads();

    // ---- phase 2b: A1 = embg@W1a, A2 = embg@W1b
    for (int which = 0; which < 2; ++which) {
        const unsigned short* WT = which ? W1bT : W1aT;
        unsigned short* op = which ? out2 : out1;
        acc = (f32x4)0.f;
        #pragma unroll
        for (int s = 0; s < 8; ++s) {
            const int k0 = s * 32;
            const short8 af = *(const short8*)&H2s[tx * FSTR + k0 + q * 8];
            const short8 bfr = *(const short8*)(WT + (size_t)col * 256 + k0 + q * 8);
            acc = __builtin_amdgcn_mfma_f32_16x16x32_bf16(af, bfr, acc, 0, 0, 0);
        }
        #pragma unroll
        for (int r = 0; r < 4; ++r)
            op[(size_t)(m0 + q * 4 + r) * 256 + col] = f2bf(acc[r]);
    }
}

// ---------------------------------------------------------------------------
// Fused pair MLP + CE. Grid 256 x 512 threads; PTILES=4 tiles of 64 pairs per
// block. Wave w: pt=w&1 (32 pairs), cg=w>>1 (64 cols). W2 fragments for the
// wave's cols preloaded ONCE into 32 short8 registers (128 VGPR) — the K-loop
// is pure LDS + MFMA (no global loads, no vmcnt waits).
// ---------------------------------------------------------------------------
__global__ __launch_bounds__(512, 1) void pair_k(
    const unsigned short* __restrict__ A1t, const unsigned short* __restrict__ A2t,
    const float* __restrict__ b1, const unsigned short* __restrict__ W2T,
    const float* __restrict__ b2, const unsigned short* __restrict__ WfT,
    const float* __restrict__ bfv,
    const int* __restrict__ sel_b, const int* __restrict__ sel_i,
    const int* __restrict__ sel_j, const int* __restrict__ golden,
    float* __restrict__ out)
{
    __shared__ __align__(16) unsigned short sbuf[64 * H1STR];  // H1 then H2
    __shared__ __align__(16) unsigned short b1s[256];
    __shared__ float Lg[64 * 8];
    __shared__ int sidx[64 * PTILES], didx[64 * PTILES], gold[64 * PTILES];

    const int tid = threadIdx.x;
    const int w = tid >> 6;          // 0..7
    const int lane = tid & 63;
    const int q = lane >> 4;
    const int tx = lane & 15;
    const int m = lane & 31;
    const int hh = lane >> 5;
    const int e0 = blockIdx.x * 64 * PTILES;

    // sel staging for all tiles (256 pairs, coalesced)
    if (tid < 64 * PTILES) {
        const int e = e0 + tid;
        const int b = sel_b[e];
        sidx[tid] = b * N_PER_B + sel_i[e];
        didx[tid] = b * N_PER_B + sel_j[e];
        gold[tid] = golden[e];
    }
    if (tid < 256) b1s[tid] = f2bf(b1[tid]);

    // ---- W2 fragment preload (once per block): 32 x short8 = 128 VGPR
    const int pt = w & 1;
    const int cg = w >> 1;
    short8 Breg[32];                 // [cc*16 + s]
    {
        const unsigned short* bb = W2T + (size_t)(cg * 64 + m) * 256 + hh * 8;
        #pragma unroll
        for (int cc = 0; cc < 2; ++cc)
            #pragma unroll
            for (int s = 0; s < 16; ++s)
                Breg[cc * 16 + s] = *(const short8*)(bb + (size_t)cc * 32 * 256 + s * 16);
    }
    __syncthreads();

    float total = 0.f;

    for (int t = 0; t < PTILES; ++t) {
        // ---- gather h1: half-wave (32 lanes) per pair-row, contiguous 16B/lane
        {
            const int hw = tid >> 5;          // 0..15
            #pragma unroll
            for (int j = 0; j < 4; ++j) {
                const int p = j * 16 + hw;
                const unsigned short* r1 = A1t + (size_t)sidx[t * 64 + p] * 256 + m * 8;
                const unsigned short* r2 = A2t + (size_t)didx[t * 64 + p] * 256 + m * 8;
                const uint4 u1 = *(const uint4*)r1;
                const uint4 u2 = *(const uint4*)r2;
                const uint4 ub = *(const uint4*)(b1s + m * 8);
                uint2 lo2, hi2;
                lo2.x = addrelu2(u1.x, u2.x, ub.x);
                lo2.y = addrelu2(u1.y, u2.y, ub.y);
                hi2.x = addrelu2(u1.z, u2.z, ub.z);
                hi2.y = addrelu2(u1.w, u2.w, ub.w);
                unsigned short* dbase = sbuf + p * H1STR + m * 8;
                *(uint2*)(dbase) = lo2;
                *(uint2*)(dbase + 4) = hi2;
            }
        }
        __syncthreads();

        // ---- main GEMM: pure LDS + register-B MFMA
        f32x16 acc0 = (f32x16)0.f;
        f32x16 acc1 = (f32x16)0.f;
        {
            const unsigned short* arow = sbuf + (size_t)(pt * 32 + m) * H1STR + hh * 8;
            #pragma unroll
            for (int s = 0; s < 16; ++s) {
                const short8 af = ld_frag(arow + s * 16);
                acc0 = __builtin_amdgcn_mfma_f32_32x32x16_bf16(af, Breg[s], acc0, 0, 0, 0);
                acc1 = __builtin_amdgcn_mfma_f32_32x32x16_bf16(af, Breg[16 + s], acc1, 0, 0, 0);
            }
        }
        __syncthreads();   // all H1 reads complete before overwrite

        // ---- epilogue: h2 = relu(acc + b2) -> sbuf (as H2)
        #pragma unroll
        for (int cc = 0; cc < 2; ++cc) {
            const f32x16* ap = cc ? &acc1 : &acc0;
            const int col = cg * 64 + cc * 32 + m;
            const float bv = b2[col];
            #pragma unroll
            for (int reg = 0; reg < 16; ++reg) {
                const int prow = pt * 32 + (reg & 3) + 8 * (reg >> 2) + 4 * hh;
                sbuf[prow * H1STR + col] = f2bf(fmaxf((*ap)[reg] + bv, 0.f));
            }
        }
        __syncthreads();

        // ---- logits = h2 @ Wfold (waves 0..3, 16 rows each)
        if (w < 4) {
            f32x4 accL = (f32x4)0.f;
            const unsigned short* a2row = sbuf + (size_t)(w * 16 + tx) * H1STR + q * 8;
            const unsigned short* bWf = WfT + (size_t)tx * 256 + q * 8;
            #pragma unroll
            for (int s = 0; s < 8; ++s) {
                const short8 af = ld_frag(a2row + s * 32);
                const short8 bfr = *(const short8*)(bWf + s * 32);
                accL = __builtin_amdgcn_mfma_f32_16x16x32_bf16(af, bfr, accL, 0, 0, 0);
            }
            if (tx < NET) {
                const float bb = bfv[tx];
                #pragma unroll
                for (int reg = 0; reg < 4; ++reg)
                    Lg[(w * 16 + q * 4 + reg) * 8 + tx] = accL[reg] + bb;
            }
        }
        __syncthreads();

        // ---- CE over this tile's 64 pairs (wave 0); Lg is separate from sbuf,
        // so next tile's gather can start at the next barrier without racing.
        if (tid < 64) {
            float lg[NET];
            #pragma unroll
            for (int tt = 0; tt < NET; ++tt) lg[tt] = Lg[tid * 8 + tt];
            float mx = lg[0];
            #pragma unroll
            for (int tt = 1; tt < NET; ++tt) mx = fmaxf(mx, lg[tt]);
            float s = 0.f;
            #pragma unroll
            for (int tt = 0; tt < NET; ++tt) s += expf(lg[tt] - mx);
            float ls = mx + logf(s) - lg[gold[t * 64 + tid]];
            #pragma unroll
            for (int off = 32; off >= 1; off >>= 1) ls += __shfl_xor(ls, off);
            total += ls;
        }
        __syncthreads();
    }

    if (tid == 0) atomicAdd(out, total * (1.0f / NSEL));
}

// ---------------------------------------------------------------------------
extern "C" void kernel_launch(void* const* d_in, const int* in_sizes, int n_in,
                              void* d_out, int out_size, void* d_ws, size_t ws_size,
                              hipStream_t stream) {
    (void)in_sizes; (void)n_in; (void)out_size; (void)ws_size;
    const float* x      = (const float*)d_in[0];
    const int*   eidx   = (const int*)d_in[1];
    const float* eattr  = (const float*)d_in[2];
    const float* props  = (const float*)d_in[3];
    const int*   sel_b  = (const int*)d_in[4];
    const int*   sel_i  = (const int*)d_in[5];
    const int*   sel_j  = (const int*)d_in[6];
    const int*   golden = (const int*)d_in[7];
    const float* W_prop = (const float*)d_in[8];
    const float* b_prop = (const float*)d_in[9];
    const float* W_in   = (const float*)d_in[10];
    const float* b_in   = (const float*)d_in[11];
    const float* W_msg  = (const float*)d_in[12];
    const float* b_msg  = (const float*)d_in[13];
    const float* W_upd  = (const float*)d_in[14];
    const float* b_upd  = (const float*)d_in[15];
    const float* W_add  = (const float*)d_in[16];
    const float* b_add  = (const float*)d_in[17];
    const float* W1     = (const float*)d_in[18];
    const float* b1     = (const float*)d_in[19];
    const float* W2     = (const float*)d_in[20];
    const float* b2     = (const float*)d_in[21];
    const float* W3     = (const float*)d_in[22];
    const float* b3     = (const float*)d_in[23];
    const float* W_out  = (const float*)d_in[24];
    const float* b_out  = (const float*)d_in[25];

    const size_t SEG = (size_t)BN * 256;
    unsigned short* P0   = (unsigned short*)d_ws;   // P even rounds; final A1
    unsigned short* P1   = P0 + SEG;                // P odd rounds
    unsigned short* hA   = P1 + SEG;                // h double-buffer; final A2
    unsigned short* hB   = hA + SEG;
    unsigned short* ETc  = hB + SEG;                // [NE][256] CSR-ordered
    unsigned short* wbf  = ETc + (size_t)NE * 256;
    unsigned short* W_inT  = wbf;                   // [256][192]
    unsigned short* WmT    = wbf + 49152;
    unsigned short* WuaT   = WmT + 65536;
    unsigned short* WubT   = WuaT + 65536;
    unsigned short* W_addT = WubT + 65536;
    unsigned short* W1aT   = W_addT + 65536;
    unsigned short* W1bT   = W1aT + 65536;
    unsigned short* W2T    = W1bT + 65536;
    unsigned short* WfT    = W2T + 65536;           // [16][256]
    float* prop_add = (float*)(WfT + 4096);         // [64][256]
    float* bfv = prop_add + 64 * 256;               // [16]
    int* deg       = (int*)(bfv + 16);
    int* row_start = deg + 4096;                    // [4097]
    int* cursor    = row_start + 4104;
    int* srcs      = cursor + 4096;                 // [NE]
    int* epos      = srcs + NE;                     // [NE]

    hipMemsetAsync(deg, 0, 4096 * sizeof(int), stream);
    k_hist<<<NE / 256, 256, 0, stream>>>(eidx, deg);
    csr_scan<<<1, 256, 0, stream>>>(deg, row_start, cursor);
    csr_scatter<<<NE / 256, 256, 0, stream>>>(eidx, cursor, srcs, epos);
    k_pre<<<577, 256, 0, stream>>>(W_in, W_msg, W_upd, W_add, W1, W2, W3, b3,
                                   W_out, b_out, props, W_prop, b_prop, b_add,
                                   b_msg, eattr, epos, wbf, WfT, bfv, prop_add, ETc);

    // round 0: h0 = relu(x@W_in+b) -> hA; P0 = h0@Wm
    fstep<<<256, 1024, 0, stream>>>(x, nullptr, nullptr, ETc, row_start, srcs,
                                    W_inT, nullptr, b_in, WmT, nullptr, nullptr, nullptr,
                                    hA, P0, nullptr, 0);
    // rounds 1..3: agg(P) -> h' -> P'
    fstep<<<256, 1024, 0, stream>>>(nullptr, hA, P0, ETc, row_start, srcs,
                                    WuaT, WubT, b_upd, WmT, nullptr, nullptr, nullptr,
                                    hB, P1, nullptr, 1);
    fstep<<<256, 1024, 0, stream>>>(nullptr, hB, P1, ETc, row_start, srcs,
                                    WuaT, WubT, b_upd, WmT, nullptr, nullptr, nullptr,
                                    hA, P0, nullptr, 1);
    fstep<<<256, 1024, 0, stream>>>(nullptr, hA, P0, ETc, row_start, srcs,
                                    WuaT, WubT, b_upd, WmT, nullptr, nullptr, nullptr,
                                    hB, P1, nullptr, 1);
    // final: agg(P1) -> h4 -> embg -> A1 (P0), A2 (hA)
    fstep<<<256, 1024, 0, stream>>>(nullptr, hB, P1, ETc, row_start, srcs,
                                    WuaT, WubT, b_upd, W_addT, prop_add, W1aT, W1bT,
                                    nullptr, P0, hA, 2);

    hipMemsetAsync(d_out, 0, sizeof(float), stream);
    pair_k<<<256, 512, 0, stream>>>(P0, hA, b1, W2T, b2, WfT, bfv,
                                    sel_b, sel_i, sel_j, golden, (float*)d_out);
}